// Round 16
// baseline (547.934 us; speedup 1.0000x reference)
//
#include <hip/hip_runtime.h>
#include <hip/hip_bf16.h>

// Problem constants
#define T_TOK 4096
#define HID   3584
#define NH    28
#define NKV   4
#define HD    128
#define SEG   4
#define LSEQ  1024
#define KDIM  3584   // K of all GEMMs (HID == NH*HD)
#define BKG   64     // GEMM K-tile
#define NCVT  128    // cvt blocks fused into attn

typedef __attribute__((ext_vector_type(8))) short bf16x8;
typedef __attribute__((ext_vector_type(4))) float f32x4;

#define GLOAD16(g, l) __builtin_amdgcn_global_load_lds( \
    (const __attribute__((address_space(1))) void*)(g), \
    (__attribute__((address_space(3))) void*)(l), 16, 0, 0)

__device__ __forceinline__ unsigned short f2bf(float f) {
    unsigned u = __float_as_uint(f);
    return (unsigned short)((u + 0x7fffu + ((u >> 16) & 1u)) >> 16);
}
__device__ __forceinline__ float bf2f(unsigned short u) {
    return __uint_as_float(((unsigned)u) << 16);
}

__device__ __forceinline__ f32x4 mfma16(bf16x8 a, bf16x8 b, f32x4 c) {
    return __builtin_amdgcn_mfma_f32_16x16x32_bf16(a, b, c, 0, 0, 0);
}

// ---------------- fused front conversion (x parity-split + 6 weight matrices) ----------------
#define XN4  3670016
#define WQ4  3211264
#define WK4  458752
__global__ void cvt_front(const float* __restrict__ x,
                          const float* __restrict__ wq, const float* __restrict__ wqg,
                          const float* __restrict__ wk, const float* __restrict__ wkg,
                          const float* __restrict__ wv, const float* __restrict__ wvg,
                          unsigned short* __restrict__ xu, unsigned short* __restrict__ xg,
                          unsigned short* __restrict__ wqb, unsigned short* __restrict__ wqgb,
                          unsigned short* __restrict__ wkb, unsigned short* __restrict__ wkgb,
                          unsigned short* __restrict__ wvb, unsigned short* __restrict__ wvgb) {
    size_t i = (size_t)blockIdx.x * 256 + threadIdx.x;
    if (i < XN4) {   // x: parity-compacted split
        int t = (int)(i / (HID / 4));
        int c = (int)(i - (size_t)t * (HID / 4));
        float4 v = reinterpret_cast<const float4*>(x)[i];
        ushort4 o;
        o.x = f2bf(v.x); o.y = f2bf(v.y); o.z = f2bf(v.z); o.w = f2bf(v.w);
        unsigned short* dst = ((t & 1) ? xg : xu) + (size_t)(t >> 1) * HID + c * 4;
        *reinterpret_cast<ushort4*>(dst) = o;
        return;
    }
    i -= XN4;
    const float* s; unsigned short* d;
    if (i < 2 * (size_t)WQ4) {
        if (i < WQ4) { s = wq; d = wqb; } else { i -= WQ4; s = wqg; d = wqgb; }
    } else {
        i -= 2 * (size_t)WQ4;
        size_t seg = i / WK4; i -= seg * WK4;
        switch (seg) {
            case 0: s = wk;  d = wkb;  break;
            case 1: s = wkg; d = wkgb; break;
            case 2: s = wv;  d = wvb;  break;
            default: s = wvg; d = wvgb; break;
        }
    }
    float4 v = reinterpret_cast<const float4*>(s)[i];
    ushort4 o;
    o.x = f2bf(v.x); o.y = f2bf(v.y); o.z = f2bf(v.z); o.w = f2bf(v.w);
    reinterpret_cast<ushort4*>(d)[i] = o;
}

// ---------------- 256x256 8-phase GEMM core (R1/R7-proven), with K-range ----------------
__device__ __forceinline__ void gemm256_core(const unsigned short* __restrict__ Aptr,
                                             const unsigned short* __restrict__ Bptr,
                                             unsigned short* ldsbase, f32x4 (&acc)[8][4],
                                             int kb, int kend) {
    const int tid = threadIdx.x;               // 0..511
    const int lane = tid & 63, w = tid >> 6;
    const int wr = w >> 2, wc = w & 3;         // wave grid 2M x 4N
    const int lr = lane & 15, lkg = lane >> 4;
    char* const L = (char*)ldsbase;

    int src_off[4];
#pragma unroll
    for (int j = 0; j < 4; j++) {
        int r = j * 64 + (tid >> 3);
        int clog = (tid & 7) ^ ((tid >> 3) & 7);
        src_off[j] = r * KDIM + clog * 8;
    }
    const int aoff0 = (wr * 128 + lr) * 128 + ((lkg ^ (lr & 7)) << 4);
    const int boff0 = (wc * 64 + lr) * 128 + ((lkg ^ (lr & 7)) << 4) + 32768;

    bf16x8 a[4][2], b[4][2];
#pragma unroll
    for (int m = 0; m < 8; m++)
#pragma unroll
        for (int n = 0; n < 4; n++) acc[m][n] = (f32x4){0.f, 0.f, 0.f, 0.f};

#define STG_A(buf, k0, h) do { _Pragma("unroll") for (int jj = 0; jj < 2; jj++) { \
    int j = (h) * 2 + jj; \
    GLOAD16(Aptr + src_off[j] + (k0), L + (buf) * 65536 + j * 8192 + tid * 16); } } while (0)
#define STG_B(buf, k0, h) do { _Pragma("unroll") for (int jj = 0; jj < 2; jj++) { \
    int j = (h) * 2 + jj; \
    GLOAD16(Bptr + src_off[j] + (k0), L + (buf) * 65536 + 32768 + j * 8192 + tid * 16); } } while (0)
#define RD_A(buf, mh) do { _Pragma("unroll") for (int mm = 0; mm < 4; mm++) { \
    int ro = (buf) * 65536 + aoff0 + ((mh) * 4 + mm) * 2048; \
    a[mm][0] = *(const bf16x8*)(L + ro); \
    a[mm][1] = *(const bf16x8*)(L + (ro ^ 64)); } } while (0)
#define RD_B(buf, nh) do { _Pragma("unroll") for (int nn = 0; nn < 2; nn++) { \
    int ro = (buf) * 65536 + boff0 + ((nh) * 2 + nn) * 2048; \
    b[(nh) * 2 + nn][0] = *(const bf16x8*)(L + ro); \
    b[(nh) * 2 + nn][1] = *(const bf16x8*)(L + (ro ^ 64)); } } while (0)
#define MM(mh, nh) do { _Pragma("unroll") for (int mm = 0; mm < 4; mm++) \
    _Pragma("unroll") for (int nn = 0; nn < 2; nn++) \
    _Pragma("unroll") for (int ks = 0; ks < 2; ks++) \
        acc[(mh) * 4 + mm][(nh) * 2 + nn] = \
            mfma16(a[mm][ks], b[(nh) * 2 + nn][ks], acc[(mh) * 4 + mm][(nh) * 2 + nn]); } while (0)
#define BAR   asm volatile("s_barrier" ::: "memory")
#define LGKM0 do { asm volatile("s_waitcnt lgkmcnt(0)" ::: "memory"); \
                   __builtin_amdgcn_sched_barrier(0); } while (0)
#define VMC4  asm volatile("s_waitcnt vmcnt(4)" ::: "memory")
#define PHI   __builtin_amdgcn_s_setprio(1)
#define PLO   __builtin_amdgcn_s_setprio(0)

    STG_A(0, kb, 0); STG_A(0, kb, 1); STG_B(0, kb, 0); STG_B(0, kb, 1);
    STG_B(1, kb + BKG, 0); STG_B(1, kb + BKG, 1);
    VMC4;   // 12 issued, wait <=4 outstanding -> buf0's 8 landed
    BAR;

    const int iters = (kend - kb) / (2 * BKG);
#pragma unroll 1
    for (int t = 0; t < iters; ++t) {
        int k1 = kb + (2 * t + 1) * BKG;
        int k2 = kb + (2 * t + 2) * BKG; if (k2 > kend - BKG) k2 = kend - BKG;
        int k3 = kb + (2 * t + 3) * BKG; if (k3 > kend - BKG) k3 = kend - BKG;
        // P1: compute buf0 (m0-3 x n0-1)
        RD_A(0, 0); RD_B(0, 0); STG_A(1, k1, 0);
        BAR; LGKM0; PHI; MM(0, 0); PLO; BAR;
        // P2: (m0-3 x n2-3)
        RD_B(0, 1); STG_A(1, k1, 1);
        BAR; LGKM0; PHI; MM(0, 1); PLO; BAR;
        // P3: (m4-7 x n0-1); buf0.B reads done -> stage next buf0.B
        RD_A(0, 1); STG_B(0, k2, 0);
        BAR; LGKM0; PHI; MM(1, 0); PLO; BAR;
        // P4: counted wait -> buf1 (P1/P2 A + prev B) landed
        STG_B(0, k2, 1);
        BAR; LGKM0; PHI; MM(1, 1); PLO; VMC4; BAR;
        // P5: compute buf1
        RD_A(1, 0); RD_B(1, 0); STG_A(0, k2, 0);
        BAR; LGKM0; PHI; MM(0, 0); PLO; BAR;
        // P6
        RD_B(1, 1); STG_A(0, k2, 1);
        BAR; LGKM0; PHI; MM(0, 1); PLO; BAR;
        // P7
        RD_A(1, 1); STG_B(1, k3, 0);
        BAR; LGKM0; PHI; MM(1, 0); PLO; BAR;
        // P8: counted wait -> buf0 (P3-P6) landed for next iter's P1
        STG_B(1, k3, 1);
        BAR; LGKM0; PHI; MM(1, 1); PLO; VMC4; BAR;
    }
    asm volatile("s_waitcnt vmcnt(0)" ::: "memory");

#undef STG_A
#undef STG_B
#undef RD_A
#undef RD_B
#undef MM
#undef BAR
#undef LGKM0
#undef VMC4
#undef PHI
#undef PLO
}

// ---------------- fused QKV projection (kv quarters first, then q full-K) ----------------
__global__ __launch_bounds__(512, 2) void qkv_gemm8(
    const unsigned short* __restrict__ xu, const unsigned short* __restrict__ xg,
    const unsigned short* __restrict__ wq0, const unsigned short* __restrict__ wk0,
    const unsigned short* __restrict__ wv0, const unsigned short* __restrict__ wq1,
    const unsigned short* __restrict__ wk1, const unsigned short* __restrict__ wv1,
    const float* __restrict__ bq0, const float* __restrict__ bk0, const float* __restrict__ bv0,
    const float* __restrict__ bq1, const float* __restrict__ bk1, const float* __restrict__ bv1,
    unsigned short* __restrict__ qp, unsigned short* __restrict__ kp,
    unsigned short* __restrict__ vp) {
    __shared__ unsigned short lds[65536];   // 128 KiB
    const int bid = blockIdx.x;
    int nb, ks, bm, kb, klen;
    if (bid < 256) {                    // kv quarter jobs (dispatch first)
        int g = bid >> 6;               // 0,1 -> k heads; 2,3 -> v heads
        int rem = bid & 63;
        ks = rem >> 4; bm = rem & 15;
        nb = 14 + g;
        kb = ks * 896; klen = 896;
    } else {                            // q full-K jobs
        int e = bid - 256;
        nb = e >> 4; bm = e & 15;
        ks = 0; kb = 0; klen = KDIM;
    }
    const int par = bm >> 3, mb = bm & 7;
    const unsigned short* A = (par ? xg : xu) + (size_t)mb * 256 * KDIM;
    const unsigned short* W;
    const float* bias;
    unsigned short* C;
    int ldc, col0;
    if (nb < 14) {
        W = (par ? wq1 : wq0) + (size_t)nb * 256 * KDIM;
        bias = (par ? bq1 : bq0); C = qp; ldc = NH * HD; col0 = nb * 256;
    } else if (nb < 16) {
        W = (par ? wk1 : wk0) + (size_t)(nb - 14) * 256 * KDIM;
        bias = (par ? bk1 : bk0); C = kp + (size_t)ks * T_TOK * (NKV * HD);
        ldc = NKV * HD; col0 = (nb - 14) * 256;
    } else {
        W = (par ? wv1 : wv0) + (size_t)(nb - 16) * 256 * KDIM;
        bias = (par ? bv1 : bv0); C = vp + (size_t)ks * T_TOK * (NKV * HD);
        ldc = NKV * HD; col0 = (nb - 16) * 256;
    }
    f32x4 acc[8][4];
    gemm256_core(A, W, lds, acc, kb, kb + klen);

    const int lane = threadIdx.x & 63, w = threadIdx.x >> 6;
    const int wr = w >> 2, wc = w & 3, lr = lane & 15, lkg = lane >> 4;
#pragma unroll
    for (int n = 0; n < 4; n++) {
        int colt = col0 + wc * 64 + n * 16 + lr;
        float bb = (ks == 0) ? bias[colt] : 0.f;
#pragma unroll
        for (int m = 0; m < 8; m++) {
#pragma unroll
            for (int rg = 0; rg < 4; rg++) {
                int tr = mb * 256 + wr * 128 + m * 16 + lkg * 4 + rg;
                int tok = 2 * tr + par;
                C[(size_t)tok * ldc + colt] = f2bf(acc[m][n][rg] + bb);
            }
        }
    }
}

// ---------------- output projection (8-phase 256^2, full K, XCD-chunked) ----------------
__global__ __launch_bounds__(512, 2) void oproj_gemm8(
    const unsigned short* __restrict__ au, const unsigned short* __restrict__ ag,
    const unsigned short* __restrict__ wo0, const unsigned short* __restrict__ wo1,
    float* __restrict__ out) {
    __shared__ unsigned short lds[65536];
    const int bid = blockIdx.x;
    const int x = bid & 7, i = bid >> 3;
    const int nb = i >> 1, bm = x * 2 + (i & 1);
    const int par = bm >> 3, mb = bm & 7;
    const unsigned short* A = (par ? ag : au) + (size_t)mb * 256 * KDIM;
    const unsigned short* W = (par ? wo1 : wo0) + (size_t)nb * 256 * KDIM;
    f32x4 acc[8][4];
    gemm256_core(A, W, lds, acc, 0, KDIM);

    const int lane = threadIdx.x & 63, w = threadIdx.x >> 6;
    const int wr = w >> 2, wc = w & 3, lr = lane & 15, lkg = lane >> 4;
#pragma unroll
    for (int n = 0; n < 4; n++) {
        int col = nb * 256 + wc * 64 + n * 16 + lr;
#pragma unroll
        for (int m = 0; m < 8; m++) {
#pragma unroll
            for (int rg = 0; rg < 4; rg++) {
                int tr = mb * 256 + wr * 128 + m * 16 + lkg * 4 + rg;
                int tok = 2 * tr + par;
                out[(size_t)tok * HID + col] = acc[m][n][rg];
            }
        }
    }
}

// ---------------- RMSNorm + RoPE (q: 1 slab, k: 4 partials) + fused vtrans ----------------
__global__ void normrope2(const unsigned short* __restrict__ qp, const unsigned short* __restrict__ kp,
                          const unsigned short* __restrict__ vp,
                          const float* __restrict__ cosb, const float* __restrict__ sinb,
                          const float* __restrict__ qn, const float* __restrict__ kn,
                          const float* __restrict__ qng, const float* __restrict__ kng,
                          unsigned short* __restrict__ q_bf, unsigned short* __restrict__ k_bf,
                          unsigned short* __restrict__ vT) {
    if (blockIdx.y == 8) {   // vtrans path: sum 4 bf16 partials -> vT
        if (blockIdx.x >= 1024) return;
        const int u = blockIdx.x * 2 + (threadIdx.x >> 7);   // 0..2047
        const int d = threadIdx.x & 127;
        const int sh = u >> 7, lb = u & 127;
        const int s = sh >> 2, hv = sh & 3;
        const size_t S = (size_t)T_TOK * NKV * HD;
        unsigned short tmp[8];
#pragma unroll
        for (int i = 0; i < 8; i++) {
            size_t idx = ((size_t)(s * LSEQ + lb * 8 + i)) * (NKV * HD) + hv * HD + d;
            tmp[i] = f2bf(bf2f(vp[idx]) + bf2f(vp[S + idx]) +
                          bf2f(vp[2 * S + idx]) + bf2f(vp[3 * S + idx]));
        }
        *(bf16x8*)(vT + ((size_t)sh * HD + d) * LSEQ + lb * 8) = *(bf16x8*)tmp;
        return;
    }
    const int t = blockIdx.x, w = threadIdx.x >> 6, lane = threadIdx.x & 63;
    const int h = blockIdx.y * 4 + w;
    const bool isq = (h < 28);
    float v0, v1;
    if (isq) {
        const unsigned short* src = qp + (size_t)t * (NH * HD) + h * HD;
        v0 = bf2f(src[lane]);
        v1 = bf2f(src[lane + 64]);
    } else {
        const unsigned short* src = kp + (size_t)t * (NKV * HD) + (h - 28) * HD;
        const size_t S = (size_t)T_TOK * NKV * HD;
        v0 = bf2f(src[lane]) + bf2f(src[S + lane]) + bf2f(src[2 * S + lane]) + bf2f(src[3 * S + lane]);
        v1 = bf2f(src[lane + 64]) + bf2f(src[S + lane + 64]) +
             bf2f(src[2 * S + lane + 64]) + bf2f(src[3 * S + lane + 64]);
    }
    float ss = v0 * v0 + v1 * v1;
#pragma unroll
    for (int off = 32; off >= 1; off >>= 1) ss += __shfl_xor(ss, off, 64);
    float inv = rsqrtf(ss * (1.f / 128.f) + 1e-6f);
    const float* wn = isq ? ((t & 1) ? qng : qn) : ((t & 1) ? kng : kn);
    float n0 = v0 * inv * wn[lane], n1 = v1 * inv * wn[lane + 64];
    float c0 = cosb[(size_t)t * HD + lane], c1 = cosb[(size_t)t * HD + lane + 64];
    float s0 = sinb[(size_t)t * HD + lane], s1 = sinb[(size_t)t * HD + lane + 64];
    float o0 = n0 * c0 - n1 * s0;
    float o1 = n1 * c1 + n0 * s1;
    unsigned short* dst = isq ? q_bf + (size_t)t * (NH * HD) + h * HD
                              : k_bf + (size_t)t * (NKV * HD) + (h - 28) * HD;
    dst[lane] = f2bf(o0);
    dst[lane + 64] = f2bf(o1);
}

// ---------------- flash attention: direct-from-L2 K/V, no barriers, QBLK=64 ----------------
// K/V per (s,hk) = 256KB -> L2-resident; fragments loaded straight to VGPRs (m169 lesson:
// don't LDS-stage cache-resident data). Only P goes through (per-wave) LDS. 256 thr = 4
// waves, each owns 16 q rows; 8KB LDS -> 4 blocks/CU. Grid NCVT cvt + 1792 attn blocks.
__global__ __launch_bounds__(256, 4) void attn_fwd(
    const unsigned short* __restrict__ q_bf, const unsigned short* __restrict__ k_bf,
    const unsigned short* __restrict__ vT,
    unsigned short* __restrict__ au, unsigned short* __restrict__ ag,
    const float* __restrict__ wof, const float* __restrict__ wogf,
    unsigned short* __restrict__ wob, unsigned short* __restrict__ wogb) {
    __shared__ unsigned short pt[4][16 * 64];    // per-wave P [q=16 rows of 128B]

    const int bid = blockIdx.x;
    const int tid = threadIdx.x;
    if (bid < NCVT) {   // fused wo/wog f32->bf16 conversion (rides attn's idle BW)
        const size_t n4 = (size_t)KDIM * KDIM / 4;
        for (size_t i = (size_t)bid * 256 + tid; i < 2 * n4; i += (size_t)NCVT * 256) {
            const float* sp = (i < n4) ? wof : wogf;
            unsigned short* dp = (i < n4) ? wob : wogb;
            size_t j = (i < n4) ? i : i - n4;
            float4 v = reinterpret_cast<const float4*>(sp)[j];
            ushort4 o;
            o.x = f2bf(v.x); o.y = f2bf(v.y); o.z = f2bf(v.z); o.w = f2bf(v.w);
            reinterpret_cast<ushort4*>(dp)[j] = o;
        }
        return;
    }
    const int e = bid - NCVT;
    const int qbk = 15 - (e / 112);            // heavy (long-K) blocks dispatch first
    const int rem = e % 112;
    const int h = rem >> 2, s = rem & 3;
    const int hk = h / 7;
    const int lane = tid & 63, w = tid >> 6;
    const int lr = lane & 15, lkg = lane >> 4;
    const int qg = qbk * 64 + w * 16 + lr;     // this lane's q row (global in segment)

    bf16x8 qf[4];
    {
        const unsigned short* qp =
            q_bf + ((size_t)(s * LSEQ + qg)) * (NH * HD) + h * HD;
#pragma unroll
        for (int kk = 0; kk < 4; kk++) qf[kk] = *(const bf16x8*)(qp + kk * 32 + lkg * 8);
    }

    float m_r = -1e30f, l_r = 0.f;
    f32x4 accO[8];
#pragma unroll
    for (int dn = 0; dn < 8; dn++) accO[dn] = (f32x4){0.f, 0.f, 0.f, 0.f};

    const float scale = 0.08838834764831843f;
    const int nkt = qbk + 1;                   // kv tiles of 64 (causal)

#pragma unroll 1
    for (int ktile = 0; ktile < nkt; ++ktile) {
        // S^T = mfma(K, Q): K fragments direct from global (L2-resident)
        // kf(n,kk) = K[kv = ktile*64 + n*16 + lr][k = kk*32 + lkg*8 .. +8]
        const unsigned short* kbase =
            k_bf + ((size_t)(s * LSEQ + ktile * 64 + lr)) * (NKV * HD) + hk * HD + lkg * 8;
        f32x4 accT[4];
#pragma unroll
        for (int n = 0; n < 4; n++) accT[n] = (f32x4){0.f, 0.f, 0.f, 0.f};
#pragma unroll
        for (int n = 0; n < 4; n++) {
#pragma unroll
            for (int kk = 0; kk < 4; kk++) {
                bf16x8 kf = *(const bf16x8*)(kbase + n * 16 * (NKV * HD) + kk * 32);
                accT[n] = mfma16(kf, qf[kk], accT[n]);   // swapped operands
            }
        }
        // scale + causal mask + in-lane row max
        float mnew = -1e30f;
#pragma unroll
        for (int n = 0; n < 4; n++) {
#pragma unroll
            for (int rg = 0; rg < 4; rg++) {
                int kvg = ktile * 64 + n * 16 + lkg * 4 + rg;
                float sv = accT[n][rg] * scale;
                sv = (kvg <= qg) ? sv : -1e30f;
                accT[n][rg] = sv;
                mnew = fmaxf(mnew, sv);
            }
        }
        mnew = fmaxf(mnew, __shfl_xor(mnew, 16, 64));
        mnew = fmaxf(mnew, __shfl_xor(mnew, 32, 64));
        // defer-max (T13)
        if (__any(mnew > m_r + 8.f)) {
            float mc = fmaxf(m_r, mnew);
            float alpha = __expf(m_r - mc);
            m_r = mc;
            l_r *= alpha;
            float ab[4];
#pragma unroll
            for (int rg = 0; rg < 4; rg++) ab[rg] = __shfl(alpha, lkg * 4 + rg, 64);
#pragma unroll
            for (int dn = 0; dn < 8; dn++)
#pragma unroll
                for (int rg = 0; rg < 4; rg++) accO[dn][rg] *= ab[rg];
        }
        // P = exp(S - m): in-lane sum + packed 8B stores to P[q=lr][kv]
        float ls = 0.f;
#pragma unroll
        for (int n = 0; n < 4; n++) {
            unsigned short p4[4];
#pragma unroll
            for (int rg = 0; rg < 4; rg++) {
                float p = __expf(accT[n][rg] - m_r);
                ls += p;
                p4[rg] = f2bf(p);
            }
            int byte = lr * 128 + ((((n * 2 + (lkg >> 1)) ^ (lr & 7))) << 4) + (lkg & 1) * 8;
            *(uint2*)((char*)pt[w] + byte) = *(uint2*)p4;
        }
        ls += __shfl_xor(ls, 16, 64);
        ls += __shfl_xor(ls, 32, 64);
        l_r += ls;
        // O += P V: V^T fragments direct from global (L2-resident)
        // vf(dn,kk2) = vT[d = dn*16 + lr][kv = ktile*64 + kk2*32 + lkg*8 .. +8]
        const unsigned short* vbase =
            vT + ((size_t)((s * NKV + hk) * HD + lr)) * LSEQ + ktile * 64 + lkg * 8;
#pragma unroll
        for (int kk2 = 0; kk2 < 2; kk2++) {
            bf16x8 pf = *(const bf16x8*)((const char*)pt[w] + lr * 128 +
                                         (((kk2 * 4 + lkg) ^ (lr & 7)) << 4));
#pragma unroll
            for (int dn = 0; dn < 8; dn++) {
                bf16x8 vf = *(const bf16x8*)(vbase + dn * 16 * LSEQ + kk2 * 32);
                accO[dn] = mfma16(pf, vf, accO[dn]);
            }
        }
    }

    // epilogue: broadcast l to accO layout (q = lkg*4+rg), divide, store
    float lb4[4];
#pragma unroll
    for (int rg = 0; rg < 4; rg++) lb4[rg] = __shfl(l_r, lkg * 4 + rg, 64);
#pragma unroll
    for (int dn = 0; dn < 8; dn++) {
#pragma unroll
        for (int rg = 0; rg < 4; rg++) {
            int row = qbk * 64 + w * 16 + lkg * 4 + rg;
            int t = s * LSEQ + row;
            unsigned short* dst = ((t & 1) ? ag : au) + (size_t)(t >> 1) * (NH * HD) +
                                  h * HD + dn * 16 + lr;
            *dst = f2bf(accO[dn][rg] / lb4[rg]);
        }
    }
}

// ---------------- host ----------------
extern "C" void kernel_launch(void* const* d_in, const int* in_sizes, int n_in,
                              void* d_out, int out_size, void* d_ws, size_t ws_size,
                              hipStream_t stream) {
    const float* x    = (const float*)d_in[0];
    const float* cosb = (const float*)d_in[1];
    const float* sinb = (const float*)d_in[2];
    const float* wq   = (const float*)d_in[3];
    const float* bq   = (const float*)d_in[4];
    const float* wk   = (const float*)d_in[5];
    const float* bk   = (const float*)d_in[6];
    const float* wv   = (const float*)d_in[7];
    const float* bv   = (const float*)d_in[8];
    const float* wo   = (const float*)d_in[9];
    const float* wqg  = (const float*)d_in[10];
    const float* bqg  = (const float*)d_in[11];
    const float* wkg  = (const float*)d_in[12];
    const float* bkg  = (const float*)d_in[13];
    const float* wvg  = (const float*)d_in[14];
    const float* bvg  = (const float*)d_in[15];
    const float* wog  = (const float*)d_in[16];
    const float* qn   = (const float*)d_in[17];
    const float* kn   = (const float*)d_in[18];
    const float* qng  = (const float*)d_in[19];
    const float* kng  = (const float*)d_in[20];
    float* out = (float*)d_out;

    char* ws = (char*)d_ws;
    size_t off = 0;
    auto alloc = [&](size_t bytes) -> char* {
        char* p = ws + off;
        off += (bytes + 255) & ~(size_t)255;
        return p;
    };
    const size_t WQ_E = (size_t)3584 * 3584;
    const size_t WK_E = (size_t)512 * 3584;
    unsigned short* wqb  = (unsigned short*)alloc(WQ_E * 2);   // dead after qkv -> reused
    unsigned short* wqgb = (unsigned short*)alloc(WQ_E * 2);   // dead after qkv -> reused
    unsigned short* wob  = (unsigned short*)alloc(WQ_E * 2);
    unsigned short* wogb = (unsigned short*)alloc(WQ_E * 2);
    unsigned short* wkb  = (unsigned short*)alloc(WK_E * 2);
    unsigned short* wkgb = (unsigned short*)alloc(WK_E * 2);
    unsigned short* wvb  = (unsigned short*)alloc(WK_E * 2);
    unsigned short* wvgb = (unsigned short*)alloc(WK_E * 2);
    unsigned short* xu   = (unsigned short*)alloc((size_t)2048 * HID * 2);
    unsigned short* xg   = (unsigned short*)alloc((size_t)2048 * HID * 2);
    unsigned short* qp = (unsigned short*)alloc((size_t)T_TOK * (NH * HD) * 2);       // 1 slab
    unsigned short* kp = (unsigned short*)alloc((size_t)4 * T_TOK * (NKV * HD) * 2);  // 4 slabs
    unsigned short* vp = (unsigned short*)alloc((size_t)4 * T_TOK * (NKV * HD) * 2);  // 4 slabs
    // q_bf/k_bf/vT alias the dead wqb/wqgb region (51.4 MB >= 29.4+4.2+4.2)
    unsigned short* q_bf = wqb;
    unsigned short* k_bf = wqb + (size_t)T_TOK * (NH * HD);
    unsigned short* vTb  = k_bf + (size_t)T_TOK * (NKV * HD);
    unsigned short* au = qp;                        // aliases dead qp region (29.4 MB)
    unsigned short* ag = au + (size_t)2048 * (NH * HD);

    if (ws_size < off) return;

    cvt_front<<<dim3((XN4 + 2 * WQ4 + 4 * WK4) / 256), 256, 0, stream>>>(
        x, wq, wqg, wk, wkg, wv, wvg,
        xu, xg, wqb, wqgb, wkb, wkgb, wvb, wvgb);

    qkv_gemm8<<<dim3(480), 512, 0, stream>>>(xu, xg, wqb, wkb, wvb, wqgb, wkgb, wvgb,
                                             bq, bk, bv, bqg, bkg, bvg, qp, kp, vp);
    normrope2<<<dim3(T_TOK, 9), 256, 0, stream>>>(qp, kp, vp, cosb, sinb,
                                                  qn, kn, qng, kng, q_bf, k_bf, vTb);
    attn_fwd<<<dim3(NCVT + 1792), 256, 0, stream>>>(q_bf, k_bf, vTb, au, ag,
                                                    wo, wog, wob, wogb);
    oproj_gemm8<<<dim3(224), 512, 0, stream>>>(au, ag, wob, wogb, out);
}

// Round 17
// 395.600 us; speedup vs baseline: 1.3851x; 1.3851x over previous
//
#include <hip/hip_runtime.h>
#include <hip/hip_bf16.h>

// Problem constants
#define T_TOK 4096
#define HID   3584
#define NH    28
#define NKV   4
#define HD    128
#define SEG   4
#define LSEQ  1024
#define KDIM  3584   // K of all GEMMs (HID == NH*HD)
#define BKG   64     // GEMM K-tile
#define NCVT  128    // cvt blocks fused into attn

typedef __attribute__((ext_vector_type(8))) short bf16x8;
typedef __attribute__((ext_vector_type(4))) float f32x4;

#define GLOAD16(g, l) __builtin_amdgcn_global_load_lds( \
    (const __attribute__((address_space(1))) void*)(g), \
    (__attribute__((address_space(3))) void*)(l), 16, 0, 0)

__device__ __forceinline__ unsigned short f2bf(float f) {
    unsigned u = __float_as_uint(f);
    return (unsigned short)((u + 0x7fffu + ((u >> 16) & 1u)) >> 16);
}
__device__ __forceinline__ float bf2f(unsigned short u) {
    return __uint_as_float(((unsigned)u) << 16);
}

__device__ __forceinline__ f32x4 mfma16(bf16x8 a, bf16x8 b, f32x4 c) {
    return __builtin_amdgcn_mfma_f32_16x16x32_bf16(a, b, c, 0, 0, 0);
}

// ---------------- fused front conversion (x parity-split + 6 weight matrices) ----------------
#define XN4  3670016
#define WQ4  3211264
#define WK4  458752
__global__ void cvt_front(const float* __restrict__ x,
                          const float* __restrict__ wq, const float* __restrict__ wqg,
                          const float* __restrict__ wk, const float* __restrict__ wkg,
                          const float* __restrict__ wv, const float* __restrict__ wvg,
                          unsigned short* __restrict__ xu, unsigned short* __restrict__ xg,
                          unsigned short* __restrict__ wqb, unsigned short* __restrict__ wqgb,
                          unsigned short* __restrict__ wkb, unsigned short* __restrict__ wkgb,
                          unsigned short* __restrict__ wvb, unsigned short* __restrict__ wvgb) {
    size_t i = (size_t)blockIdx.x * 256 + threadIdx.x;
    if (i < XN4) {   // x: parity-compacted split
        int t = (int)(i / (HID / 4));
        int c = (int)(i - (size_t)t * (HID / 4));
        float4 v = reinterpret_cast<const float4*>(x)[i];
        ushort4 o;
        o.x = f2bf(v.x); o.y = f2bf(v.y); o.z = f2bf(v.z); o.w = f2bf(v.w);
        unsigned short* dst = ((t & 1) ? xg : xu) + (size_t)(t >> 1) * HID + c * 4;
        *reinterpret_cast<ushort4*>(dst) = o;
        return;
    }
    i -= XN4;
    const float* s; unsigned short* d;
    if (i < 2 * (size_t)WQ4) {
        if (i < WQ4) { s = wq; d = wqb; } else { i -= WQ4; s = wqg; d = wqgb; }
    } else {
        i -= 2 * (size_t)WQ4;
        size_t seg = i / WK4; i -= seg * WK4;
        switch (seg) {
            case 0: s = wk;  d = wkb;  break;
            case 1: s = wkg; d = wkgb; break;
            case 2: s = wv;  d = wvb;  break;
            default: s = wvg; d = wvgb; break;
        }
    }
    float4 v = reinterpret_cast<const float4*>(s)[i];
    ushort4 o;
    o.x = f2bf(v.x); o.y = f2bf(v.y); o.z = f2bf(v.z); o.w = f2bf(v.w);
    reinterpret_cast<ushort4*>(d)[i] = o;
}

// ---------------- 256x256 8-phase GEMM core (R1/R7-proven), with K-range ----------------
__device__ __forceinline__ void gemm256_core(const unsigned short* __restrict__ Aptr,
                                             const unsigned short* __restrict__ Bptr,
                                             unsigned short* ldsbase, f32x4 (&acc)[8][4],
                                             int kb, int kend) {
    const int tid = threadIdx.x;               // 0..511
    const int lane = tid & 63, w = tid >> 6;
    const int wr = w >> 2, wc = w & 3;         // wave grid 2M x 4N
    const int lr = lane & 15, lkg = lane >> 4;
    char* const L = (char*)ldsbase;

    int src_off[4];
#pragma unroll
    for (int j = 0; j < 4; j++) {
        int r = j * 64 + (tid >> 3);
        int clog = (tid & 7) ^ ((tid >> 3) & 7);
        src_off[j] = r * KDIM + clog * 8;
    }
    const int aoff0 = (wr * 128 + lr) * 128 + ((lkg ^ (lr & 7)) << 4);
    const int boff0 = (wc * 64 + lr) * 128 + ((lkg ^ (lr & 7)) << 4) + 32768;

    bf16x8 a[4][2], b[4][2];
#pragma unroll
    for (int m = 0; m < 8; m++)
#pragma unroll
        for (int n = 0; n < 4; n++) acc[m][n] = (f32x4){0.f, 0.f, 0.f, 0.f};

#define STG_A(buf, k0, h) do { _Pragma("unroll") for (int jj = 0; jj < 2; jj++) { \
    int j = (h) * 2 + jj; \
    GLOAD16(Aptr + src_off[j] + (k0), L + (buf) * 65536 + j * 8192 + tid * 16); } } while (0)
#define STG_B(buf, k0, h) do { _Pragma("unroll") for (int jj = 0; jj < 2; jj++) { \
    int j = (h) * 2 + jj; \
    GLOAD16(Bptr + src_off[j] + (k0), L + (buf) * 65536 + 32768 + j * 8192 + tid * 16); } } while (0)
#define RD_A(buf, mh) do { _Pragma("unroll") for (int mm = 0; mm < 4; mm++) { \
    int ro = (buf) * 65536 + aoff0 + ((mh) * 4 + mm) * 2048; \
    a[mm][0] = *(const bf16x8*)(L + ro); \
    a[mm][1] = *(const bf16x8*)(L + (ro ^ 64)); } } while (0)
#define RD_B(buf, nh) do { _Pragma("unroll") for (int nn = 0; nn < 2; nn++) { \
    int ro = (buf) * 65536 + boff0 + ((nh) * 2 + nn) * 2048; \
    b[(nh) * 2 + nn][0] = *(const bf16x8*)(L + ro); \
    b[(nh) * 2 + nn][1] = *(const bf16x8*)(L + (ro ^ 64)); } } while (0)
#define MM(mh, nh) do { _Pragma("unroll") for (int mm = 0; mm < 4; mm++) \
    _Pragma("unroll") for (int nn = 0; nn < 2; nn++) \
    _Pragma("unroll") for (int ks = 0; ks < 2; ks++) \
        acc[(mh) * 4 + mm][(nh) * 2 + nn] = \
            mfma16(a[mm][ks], b[(nh) * 2 + nn][ks], acc[(mh) * 4 + mm][(nh) * 2 + nn]); } while (0)
#define BAR   asm volatile("s_barrier" ::: "memory")
#define LGKM0 do { asm volatile("s_waitcnt lgkmcnt(0)" ::: "memory"); \
                   __builtin_amdgcn_sched_barrier(0); } while (0)
#define VMC4  asm volatile("s_waitcnt vmcnt(4)" ::: "memory")
#define PHI   __builtin_amdgcn_s_setprio(1)
#define PLO   __builtin_amdgcn_s_setprio(0)

    STG_A(0, kb, 0); STG_A(0, kb, 1); STG_B(0, kb, 0); STG_B(0, kb, 1);
    STG_B(1, kb + BKG, 0); STG_B(1, kb + BKG, 1);
    VMC4;   // 12 issued, wait <=4 outstanding -> buf0's 8 landed
    BAR;

    const int iters = (kend - kb) / (2 * BKG);
#pragma unroll 1
    for (int t = 0; t < iters; ++t) {
        int k1 = kb + (2 * t + 1) * BKG;
        int k2 = kb + (2 * t + 2) * BKG; if (k2 > kend - BKG) k2 = kend - BKG;
        int k3 = kb + (2 * t + 3) * BKG; if (k3 > kend - BKG) k3 = kend - BKG;
        // P1: compute buf0 (m0-3 x n0-1)
        RD_A(0, 0); RD_B(0, 0); STG_A(1, k1, 0);
        BAR; LGKM0; PHI; MM(0, 0); PLO; BAR;
        // P2: (m0-3 x n2-3)
        RD_B(0, 1); STG_A(1, k1, 1);
        BAR; LGKM0; PHI; MM(0, 1); PLO; BAR;
        // P3: (m4-7 x n0-1); buf0.B reads done -> stage next buf0.B
        RD_A(0, 1); STG_B(0, k2, 0);
        BAR; LGKM0; PHI; MM(1, 0); PLO; BAR;
        // P4: counted wait -> buf1 (P1/P2 A + prev B) landed
        STG_B(0, k2, 1);
        BAR; LGKM0; PHI; MM(1, 1); PLO; VMC4; BAR;
        // P5: compute buf1
        RD_A(1, 0); RD_B(1, 0); STG_A(0, k2, 0);
        BAR; LGKM0; PHI; MM(0, 0); PLO; BAR;
        // P6
        RD_B(1, 1); STG_A(0, k2, 1);
        BAR; LGKM0; PHI; MM(0, 1); PLO; BAR;
        // P7
        RD_A(1, 1); STG_B(1, k3, 0);
        BAR; LGKM0; PHI; MM(1, 0); PLO; BAR;
        // P8: counted wait -> buf0 (P3-P6) landed for next iter's P1
        STG_B(1, k3, 1);
        BAR; LGKM0; PHI; MM(1, 1); PLO; VMC4; BAR;
    }
    asm volatile("s_waitcnt vmcnt(0)" ::: "memory");

#undef STG_A
#undef STG_B
#undef RD_A
#undef RD_B
#undef MM
#undef BAR
#undef LGKM0
#undef VMC4
#undef PHI
#undef PLO
}

// ---------------- fused QKV projection (kv quarters first, then q full-K) ----------------
__global__ __launch_bounds__(512, 2) void qkv_gemm8(
    const unsigned short* __restrict__ xu, const unsigned short* __restrict__ xg,
    const unsigned short* __restrict__ wq0, const unsigned short* __restrict__ wk0,
    const unsigned short* __restrict__ wv0, const unsigned short* __restrict__ wq1,
    const unsigned short* __restrict__ wk1, const unsigned short* __restrict__ wv1,
    const float* __restrict__ bq0, const float* __restrict__ bk0, const float* __restrict__ bv0,
    const float* __restrict__ bq1, const float* __restrict__ bk1, const float* __restrict__ bv1,
    unsigned short* __restrict__ qp, unsigned short* __restrict__ kp,
    unsigned short* __restrict__ vp) {
    __shared__ unsigned short lds[65536];   // 128 KiB
    const int bid = blockIdx.x;
    int nb, ks, bm, kb, klen;
    if (bid < 256) {                    // kv quarter jobs (dispatch first)
        int g = bid >> 6;               // 0,1 -> k heads; 2,3 -> v heads
        int rem = bid & 63;
        ks = rem >> 4; bm = rem & 15;
        nb = 14 + g;
        kb = ks * 896; klen = 896;
    } else {                            // q full-K jobs
        int e = bid - 256;
        nb = e >> 4; bm = e & 15;
        ks = 0; kb = 0; klen = KDIM;
    }
    const int par = bm >> 3, mb = bm & 7;
    const unsigned short* A = (par ? xg : xu) + (size_t)mb * 256 * KDIM;
    const unsigned short* W;
    const float* bias;
    unsigned short* C;
    int ldc, col0;
    if (nb < 14) {
        W = (par ? wq1 : wq0) + (size_t)nb * 256 * KDIM;
        bias = (par ? bq1 : bq0); C = qp; ldc = NH * HD; col0 = nb * 256;
    } else if (nb < 16) {
        W = (par ? wk1 : wk0) + (size_t)(nb - 14) * 256 * KDIM;
        bias = (par ? bk1 : bk0); C = kp + (size_t)ks * T_TOK * (NKV * HD);
        ldc = NKV * HD; col0 = (nb - 14) * 256;
    } else {
        W = (par ? wv1 : wv0) + (size_t)(nb - 16) * 256 * KDIM;
        bias = (par ? bv1 : bv0); C = vp + (size_t)ks * T_TOK * (NKV * HD);
        ldc = NKV * HD; col0 = (nb - 16) * 256;
    }
    f32x4 acc[8][4];
    gemm256_core(A, W, lds, acc, kb, kb + klen);

    const int lane = threadIdx.x & 63, w = threadIdx.x >> 6;
    const int wr = w >> 2, wc = w & 3, lr = lane & 15, lkg = lane >> 4;
#pragma unroll
    for (int n = 0; n < 4; n++) {
        int colt = col0 + wc * 64 + n * 16 + lr;
        float bb = (ks == 0) ? bias[colt] : 0.f;
#pragma unroll
        for (int m = 0; m < 8; m++) {
#pragma unroll
            for (int rg = 0; rg < 4; rg++) {
                int tr = mb * 256 + wr * 128 + m * 16 + lkg * 4 + rg;
                int tok = 2 * tr + par;
                C[(size_t)tok * ldc + colt] = f2bf(acc[m][n][rg] + bb);
            }
        }
    }
}

// ---------------- output projection (8-phase 256^2, full K, XCD-chunked) ----------------
__global__ __launch_bounds__(512, 2) void oproj_gemm8(
    const unsigned short* __restrict__ au, const unsigned short* __restrict__ ag,
    const unsigned short* __restrict__ wo0, const unsigned short* __restrict__ wo1,
    float* __restrict__ out) {
    __shared__ unsigned short lds[65536];
    const int bid = blockIdx.x;
    const int x = bid & 7, i = bid >> 3;
    const int nb = i >> 1, bm = x * 2 + (i & 1);
    const int par = bm >> 3, mb = bm & 7;
    const unsigned short* A = (par ? ag : au) + (size_t)mb * 256 * KDIM;
    const unsigned short* W = (par ? wo1 : wo0) + (size_t)nb * 256 * KDIM;
    f32x4 acc[8][4];
    gemm256_core(A, W, lds, acc, 0, KDIM);

    const int lane = threadIdx.x & 63, w = threadIdx.x >> 6;
    const int wr = w >> 2, wc = w & 3, lr = lane & 15, lkg = lane >> 4;
#pragma unroll
    for (int n = 0; n < 4; n++) {
        int col = nb * 256 + wc * 64 + n * 16 + lr;
#pragma unroll
        for (int m = 0; m < 8; m++) {
#pragma unroll
            for (int rg = 0; rg < 4; rg++) {
                int tr = mb * 256 + wr * 128 + m * 16 + lkg * 4 + rg;
                int tok = 2 * tr + par;
                out[(size_t)tok * HID + col] = acc[m][n][rg];
            }
        }
    }
}

// ---------------- RMSNorm + RoPE (q: 1 slab, k: 4 partials) + fused vtrans ----------------
__global__ void normrope2(const unsigned short* __restrict__ qp, const unsigned short* __restrict__ kp,
                          const unsigned short* __restrict__ vp,
                          const float* __restrict__ cosb, const float* __restrict__ sinb,
                          const float* __restrict__ qn, const float* __restrict__ kn,
                          const float* __restrict__ qng, const float* __restrict__ kng,
                          unsigned short* __restrict__ q_bf, unsigned short* __restrict__ k_bf,
                          unsigned short* __restrict__ vT) {
    if (blockIdx.y == 8) {   // vtrans path: sum 4 bf16 partials -> vT
        if (blockIdx.x >= 1024) return;
        const int u = blockIdx.x * 2 + (threadIdx.x >> 7);   // 0..2047
        const int d = threadIdx.x & 127;
        const int sh = u >> 7, lb = u & 127;
        const int s = sh >> 2, hv = sh & 3;
        const size_t S = (size_t)T_TOK * NKV * HD;
        unsigned short tmp[8];
#pragma unroll
        for (int i = 0; i < 8; i++) {
            size_t idx = ((size_t)(s * LSEQ + lb * 8 + i)) * (NKV * HD) + hv * HD + d;
            tmp[i] = f2bf(bf2f(vp[idx]) + bf2f(vp[S + idx]) +
                          bf2f(vp[2 * S + idx]) + bf2f(vp[3 * S + idx]));
        }
        *(bf16x8*)(vT + ((size_t)sh * HD + d) * LSEQ + lb * 8) = *(bf16x8*)tmp;
        return;
    }
    const int t = blockIdx.x, w = threadIdx.x >> 6, lane = threadIdx.x & 63;
    const int h = blockIdx.y * 4 + w;
    const bool isq = (h < 28);
    float v0, v1;
    if (isq) {
        const unsigned short* src = qp + (size_t)t * (NH * HD) + h * HD;
        v0 = bf2f(src[lane]);
        v1 = bf2f(src[lane + 64]);
    } else {
        const unsigned short* src = kp + (size_t)t * (NKV * HD) + (h - 28) * HD;
        const size_t S = (size_t)T_TOK * NKV * HD;
        v0 = bf2f(src[lane]) + bf2f(src[S + lane]) + bf2f(src[2 * S + lane]) + bf2f(src[3 * S + lane]);
        v1 = bf2f(src[lane + 64]) + bf2f(src[S + lane + 64]) +
             bf2f(src[2 * S + lane + 64]) + bf2f(src[3 * S + lane + 64]);
    }
    float ss = v0 * v0 + v1 * v1;
#pragma unroll
    for (int off = 32; off >= 1; off >>= 1) ss += __shfl_xor(ss, off, 64);
    float inv = rsqrtf(ss * (1.f / 128.f) + 1e-6f);
    const float* wn = isq ? ((t & 1) ? qng : qn) : ((t & 1) ? kng : kn);
    float n0 = v0 * inv * wn[lane], n1 = v1 * inv * wn[lane + 64];
    float c0 = cosb[(size_t)t * HD + lane], c1 = cosb[(size_t)t * HD + lane + 64];
    float s0 = sinb[(size_t)t * HD + lane], s1 = sinb[(size_t)t * HD + lane + 64];
    float o0 = n0 * c0 - n1 * s0;
    float o1 = n1 * c1 + n0 * s1;
    unsigned short* dst = isq ? q_bf + (size_t)t * (NH * HD) + h * HD
                              : k_bf + (size_t)t * (NKV * HD) + (h - 28) * HD;
    dst[lane] = f2bf(o0);
    dst[lane + 64] = f2bf(o1);
}

// ---------------- flash attention (swapped QK^T, QBLK=128, dbuf LDS) + fused wo cvt ----------------
__global__ __launch_bounds__(512, 4) void attn_fwd(
    const unsigned short* __restrict__ q_bf, const unsigned short* __restrict__ k_bf,
    const unsigned short* __restrict__ vT,
    unsigned short* __restrict__ au, unsigned short* __restrict__ ag,
    const float* __restrict__ wof, const float* __restrict__ wogf,
    unsigned short* __restrict__ wob, unsigned short* __restrict__ wogb) {
    __shared__ unsigned short kt[2][64 * 128];   // K tiles, swizzled
    __shared__ unsigned short vt[2][128 * 64];   // V^T tiles, swizzled
    __shared__ unsigned short pt[8][16 * 64];    // per-wave P [q=16 rows of 128B]

    const int bid = blockIdx.x;
    const int tid = threadIdx.x;
    if (bid < NCVT) {   // conversion path (no LDS use)
        const size_t n4 = (size_t)KDIM * KDIM / 4;
        for (size_t i = (size_t)bid * 512 + tid; i < 2 * n4; i += (size_t)NCVT * 512) {
            const float* sp = (i < n4) ? wof : wogf;
            unsigned short* dp = (i < n4) ? wob : wogb;
            size_t j = (i < n4) ? i : i - n4;
            float4 v = reinterpret_cast<const float4*>(sp)[j];
            ushort4 o;
            o.x = f2bf(v.x); o.y = f2bf(v.y); o.z = f2bf(v.z); o.w = f2bf(v.w);
            reinterpret_cast<ushort4*>(dp)[j] = o;
        }
        return;
    }
    const int e = bid - NCVT;
    const int qbk = 7 - (e / 112);            // heavy (long-K) blocks dispatch first
    const int rem = e % 112;
    const int h = rem >> 2, s = rem & 3;
    const int hk = h / 7;
    const int lane = tid & 63, w = tid >> 6;
    const int lr = lane & 15, lkg = lane >> 4;
    const int qg = qbk * 128 + w * 16 + lr;   // this lane's q row (global in segment)

    bf16x8 qf[4];
    {
        const unsigned short* qp =
            q_bf + ((size_t)(s * LSEQ + qg)) * (NH * HD) + h * HD;
#pragma unroll
        for (int kk = 0; kk < 4; kk++) qf[kk] = *(const bf16x8*)(qp + kk * 32 + lkg * 8);
    }
    asm volatile("s_waitcnt vmcnt(0)" ::: "memory");

    float m_r = -1e30f, l_r = 0.f;
    f32x4 accO[8];
#pragma unroll
    for (int dn = 0; dn < 8; dn++) accO[dn] = (f32x4){0.f, 0.f, 0.f, 0.f};

    const float scale = 0.08838834764831843f;
    const int nkt = 2 * qbk + 2;              // kv tiles of 64 (causal)

#define STAGE_KV(buf, ktile) do { _Pragma("unroll") for (int i = 0; i < 2; i++) { \
    int o = i * 8192 + tid * 16; \
    { int r = o >> 8; int sc = ((o >> 4) & 15) ^ (r & 7); \
      GLOAD16(k_bf + ((size_t)(s * LSEQ + (ktile) * 64 + r)) * (NKV * HD) + hk * HD + sc * 8, \
              (char*)kt[buf] + o); } \
    { int r = o >> 7; int sc = ((o >> 4) & 7) ^ (r & 7); \
      GLOAD16(vT + ((size_t)((s * NKV + hk) * HD + r)) * LSEQ + (ktile) * 64 + sc * 8, \
              (char*)vt[buf] + o); } } } while (0)

    STAGE_KV(0, 0);

#pragma unroll 1
    for (int ktile = 0; ktile < nkt; ++ktile) {
        const int cur = ktile & 1;
        if (ktile + 1 < nkt) {
            STAGE_KV(cur ^ 1, ktile + 1);                     // overlap next-tile loads
            asm volatile("s_waitcnt vmcnt(4)" ::: "memory");  // this tile's 4 landed
        } else {
            asm volatile("s_waitcnt vmcnt(0)" ::: "memory");
        }
        asm volatile("s_barrier" ::: "memory");

        // S^T = mfma(K, Q): accT[n][rg] = S[q=lr][kv = ktile*64 + n*16 + lkg*4 + rg]
        f32x4 accT[4];
#pragma unroll
        for (int n = 0; n < 4; n++) accT[n] = (f32x4){0.f, 0.f, 0.f, 0.f};
        __builtin_amdgcn_s_setprio(1);
#pragma unroll
        for (int n = 0; n < 4; n++) {
            int r = n * 16 + lr;
#pragma unroll
            for (int kk = 0; kk < 4; kk++) {
                bf16x8 kf = *(const bf16x8*)((const char*)kt[cur] + r * 256 +
                                             (((kk * 4 + lkg) ^ (r & 7)) << 4));
                accT[n] = mfma16(kf, qf[kk], accT[n]);   // swapped operands
            }
        }
        __builtin_amdgcn_s_setprio(0);
        // scale + causal mask + in-lane row max
        float mnew = -1e30f;
#pragma unroll
        for (int n = 0; n < 4; n++) {
#pragma unroll
            for (int rg = 0; rg < 4; rg++) {
                int kvg = ktile * 64 + n * 16 + lkg * 4 + rg;
                float sv = accT[n][rg] * scale;
                sv = (kvg <= qg) ? sv : -1e30f;
                accT[n][rg] = sv;
                mnew = fmaxf(mnew, sv);
            }
        }
        mnew = fmaxf(mnew, __shfl_xor(mnew, 16, 64));
        mnew = fmaxf(mnew, __shfl_xor(mnew, 32, 64));
        // defer-max (T13)
        if (__any(mnew > m_r + 8.f)) {
            float mc = fmaxf(m_r, mnew);
            float alpha = __expf(m_r - mc);
            m_r = mc;
            l_r *= alpha;
            float ab[4];
#pragma unroll
            for (int rg = 0; rg < 4; rg++) ab[rg] = __shfl(alpha, lkg * 4 + rg, 64);
#pragma unroll
            for (int dn = 0; dn < 8; dn++)
#pragma unroll
                for (int rg = 0; rg < 4; rg++) accO[dn][rg] *= ab[rg];
        }
        // P = exp(S - m): in-lane sum + packed 8B stores to P[q=lr][kv]
        float ls = 0.f;
#pragma unroll
        for (int n = 0; n < 4; n++) {
            unsigned short p4[4];
#pragma unroll
            for (int rg = 0; rg < 4; rg++) {
                float p = __expf(accT[n][rg] - m_r);
                ls += p;
                p4[rg] = f2bf(p);
            }
            int byte = lr * 128 + ((((n * 2 + (lkg >> 1)) ^ (lr & 7))) << 4) + (lkg & 1) * 8;
            *(uint2*)((char*)pt[w] + byte) = *(uint2*)p4;
        }
        ls += __shfl_xor(ls, 16, 64);
        ls += __shfl_xor(ls, 32, 64);
        l_r += ls;
        // O += P V  (pf read layout identical to P write layout above)
        __builtin_amdgcn_s_setprio(1);
#pragma unroll
        for (int kk2 = 0; kk2 < 2; kk2++) {
            bf16x8 pf = *(const bf16x8*)((const char*)pt[w] + lr * 128 +
                                         (((kk2 * 4 + lkg) ^ (lr & 7)) << 4));
#pragma unroll
            for (int dn = 0; dn < 8; dn++) {
                int r2 = dn * 16 + lr;
                bf16x8 vf = *(const bf16x8*)((const char*)vt[cur] + r2 * 128 +
                                             (((kk2 * 4 + lkg) ^ (r2 & 7)) << 4));
                accO[dn] = mfma16(pf, vf, accO[dn]);
            }
        }
        __builtin_amdgcn_s_setprio(0);
        asm volatile("s_barrier" ::: "memory");   // reads of buf[cur] done -> free for t+2
    }
#undef STAGE_KV

    // epilogue: broadcast l to accO layout (q = lkg*4+rg), divide, store
    float lb4[4];
#pragma unroll
    for (int rg = 0; rg < 4; rg++) lb4[rg] = __shfl(l_r, lkg * 4 + rg, 64);
#pragma unroll
    for (int dn = 0; dn < 8; dn++) {
#pragma unroll
        for (int rg = 0; rg < 4; rg++) {
            int row = qbk * 128 + w * 16 + lkg * 4 + rg;
            int t = s * LSEQ + row;
            unsigned short* dst = ((t & 1) ? ag : au) + (size_t)(t >> 1) * (NH * HD) +
                                  h * HD + dn * 16 + lr;
            *dst = f2bf(accO[dn][rg] / lb4[rg]);
        }
    }
}

// ---------------- host ----------------
extern "C" void kernel_launch(void* const* d_in, const int* in_sizes, int n_in,
                              void* d_out, int out_size, void* d_ws, size_t ws_size,
                              hipStream_t stream) {
    const float* x    = (const float*)d_in[0];
    const float* cosb = (const float*)d_in[1];
    const float* sinb = (const float*)d_in[2];
    const float* wq   = (const float*)d_in[3];
    const float* bq   = (const float*)d_in[4];
    const float* wk   = (const float*)d_in[5];
    const float* bk   = (const float*)d_in[6];
    const float* wv   = (const float*)d_in[7];
    const float* bv   = (const float*)d_in[8];
    const float* wo   = (const float*)d_in[9];
    const float* wqg  = (const float*)d_in[10];
    const float* bqg  = (const float*)d_in[11];
    const float* wkg  = (const float*)d_in[12];
    const float* bkg  = (const float*)d_in[13];
    const float* wvg  = (const float*)d_in[14];
    const float* bvg  = (const float*)d_in[15];
    const float* wog  = (const float*)d_in[16];
    const float* qn   = (const float*)d_in[17];
    const float* kn   = (const float*)d_in[18];
    const float* qng  = (const float*)d_in[19];
    const float* kng  = (const float*)d_in[20];
    float* out = (float*)d_out;

    char* ws = (char*)d_ws;
    size_t off = 0;
    auto alloc = [&](size_t bytes) -> char* {
        char* p = ws + off;
        off += (bytes + 255) & ~(size_t)255;
        return p;
    };
    const size_t WQ_E = (size_t)3584 * 3584;
    const size_t WK_E = (size_t)512 * 3584;
    unsigned short* wqb  = (unsigned short*)alloc(WQ_E * 2);   // dead after qkv -> reused
    unsigned short* wqgb = (unsigned short*)alloc(WQ_E * 2);   // dead after qkv -> reused
    unsigned short* wob  = (unsigned short*)alloc(WQ_E * 2);
    unsigned short* wogb = (unsigned short*)alloc(WQ_E * 2);
    unsigned short* wkb  = (unsigned short*)alloc(WK_E * 2);
    unsigned short* wkgb = (unsigned short*)alloc(WK_E * 2);
    unsigned short* wvb  = (unsigned short*)alloc(WK_E * 2);
    unsigned short* wvgb = (unsigned short*)alloc(WK_E * 2);
    unsigned short* xu   = (unsigned short*)alloc((size_t)2048 * HID * 2);
    unsigned short* xg   = (unsigned short*)alloc((size_t)2048 * HID * 2);
    unsigned short* qp = (unsigned short*)alloc((size_t)T_TOK * (NH * HD) * 2);       // 1 slab
    unsigned short* kp = (unsigned short*)alloc((size_t)4 * T_TOK * (NKV * HD) * 2);  // 4 slabs
    unsigned short* vp = (unsigned short*)alloc((size_t)4 * T_TOK * (NKV * HD) * 2);  // 4 slabs
    // q_bf/k_bf/vT alias the dead wqb/wqgb region (51.4 MB >= 29.4+4.2+4.2)
    unsigned short* q_bf = wqb;
    unsigned short* k_bf = wqb + (size_t)T_TOK * (NH * HD);
    unsigned short* vTb  = k_bf + (size_t)T_TOK * (NKV * HD);
    unsigned short* au = qp;                        // aliases dead qp region (29.4 MB)
    unsigned short* ag = au + (size_t)2048 * (NH * HD);

    if (ws_size < off) return;

    cvt_front<<<dim3((XN4 + 2 * WQ4 + 4 * WK4) / 256), 256, 0, stream>>>(
        x, wq, wqg, wk, wkg, wv, wvg,
        xu, xg, wqb, wqgb, wkb, wkgb, wvb, wvgb);

    qkv_gemm8<<<dim3(480), 512, 0, stream>>>(xu, xg, wqb, wkb, wvb, wqgb, wkgb, wvgb,
                                             bq, bk, bv, bqg, bkg, bvg, qp, kp, vp);
    normrope2<<<dim3(T_TOK, 9), 256, 0, stream>>>(qp, kp, vp, cosb, sinb,
                                                  qn, kn, qng, kng, q_bf, k_bf, vTb);
    attn_fwd<<<dim3(NCVT + 896), 512, 0, stream>>>(q_bf, k_bf, vTb, au, ag,
                                                   wo, wog, wob, wogb);
    oproj_gemm8<<<dim3(224), 512, 0, stream>>>(au, ag, wob, wogb, out);
}

// Round 18
// 391.686 us; speedup vs baseline: 1.3989x; 1.0100x over previous
//
#include <hip/hip_runtime.h>
#include <hip/hip_bf16.h>

// Problem constants
#define T_TOK 4096
#define HID   3584
#define NH    28
#define NKV   4
#define HD    128
#define SEG   4
#define LSEQ  1024
#define KDIM  3584   // K of all GEMMs (HID == NH*HD)
#define BKG   64     // GEMM K-tile
#define NCVT  128    // cvt blocks fused into attn

typedef __attribute__((ext_vector_type(8))) short bf16x8;
typedef __attribute__((ext_vector_type(4))) float f32x4;

#define GLOAD16(g, l) __builtin_amdgcn_global_load_lds( \
    (const __attribute__((address_space(1))) void*)(g), \
    (__attribute__((address_space(3))) void*)(l), 16, 0, 0)

__device__ __forceinline__ unsigned short f2bf(float f) {
    unsigned u = __float_as_uint(f);
    return (unsigned short)((u + 0x7fffu + ((u >> 16) & 1u)) >> 16);
}
__device__ __forceinline__ float bf2f(unsigned short u) {
    return __uint_as_float(((unsigned)u) << 16);
}

__device__ __forceinline__ f32x4 mfma16(bf16x8 a, bf16x8 b, f32x4 c) {
    return __builtin_amdgcn_mfma_f32_16x16x32_bf16(a, b, c, 0, 0, 0);
}

// ---------------- fused front conversion (x parity-split + 6 weight matrices) ----------------
#define XN4  3670016
#define WQ4  3211264
#define WK4  458752
__global__ void cvt_front(const float* __restrict__ x,
                          const float* __restrict__ wq, const float* __restrict__ wqg,
                          const float* __restrict__ wk, const float* __restrict__ wkg,
                          const float* __restrict__ wv, const float* __restrict__ wvg,
                          unsigned short* __restrict__ xu, unsigned short* __restrict__ xg,
                          unsigned short* __restrict__ wqb, unsigned short* __restrict__ wqgb,
                          unsigned short* __restrict__ wkb, unsigned short* __restrict__ wkgb,
                          unsigned short* __restrict__ wvb, unsigned short* __restrict__ wvgb) {
    size_t i = (size_t)blockIdx.x * 256 + threadIdx.x;
    if (i < XN4) {   // x: parity-compacted split
        int t = (int)(i / (HID / 4));
        int c = (int)(i - (size_t)t * (HID / 4));
        float4 v = reinterpret_cast<const float4*>(x)[i];
        ushort4 o;
        o.x = f2bf(v.x); o.y = f2bf(v.y); o.z = f2bf(v.z); o.w = f2bf(v.w);
        unsigned short* dst = ((t & 1) ? xg : xu) + (size_t)(t >> 1) * HID + c * 4;
        *reinterpret_cast<ushort4*>(dst) = o;
        return;
    }
    i -= XN4;
    const float* s; unsigned short* d;
    if (i < 2 * (size_t)WQ4) {
        if (i < WQ4) { s = wq; d = wqb; } else { i -= WQ4; s = wqg; d = wqgb; }
    } else {
        i -= 2 * (size_t)WQ4;
        size_t seg = i / WK4; i -= seg * WK4;
        switch (seg) {
            case 0: s = wk;  d = wkb;  break;
            case 1: s = wkg; d = wkgb; break;
            case 2: s = wv;  d = wvb;  break;
            default: s = wvg; d = wvgb; break;
        }
    }
    float4 v = reinterpret_cast<const float4*>(s)[i];
    ushort4 o;
    o.x = f2bf(v.x); o.y = f2bf(v.y); o.z = f2bf(v.z); o.w = f2bf(v.w);
    reinterpret_cast<ushort4*>(d)[i] = o;
}

// ---------------- 256x256 8-phase GEMM core (R1/R7-proven), with K-range ----------------
__device__ __forceinline__ void gemm256_core(const unsigned short* __restrict__ Aptr,
                                             const unsigned short* __restrict__ Bptr,
                                             unsigned short* ldsbase, f32x4 (&acc)[8][4],
                                             int kb, int kend) {
    const int tid = threadIdx.x;               // 0..511
    const int lane = tid & 63, w = tid >> 6;
    const int wr = w >> 2, wc = w & 3;         // wave grid 2M x 4N
    const int lr = lane & 15, lkg = lane >> 4;
    char* const L = (char*)ldsbase;

    int src_off[4];
#pragma unroll
    for (int j = 0; j < 4; j++) {
        int r = j * 64 + (tid >> 3);
        int clog = (tid & 7) ^ ((tid >> 3) & 7);
        src_off[j] = r * KDIM + clog * 8;
    }
    const int aoff0 = (wr * 128 + lr) * 128 + ((lkg ^ (lr & 7)) << 4);
    const int boff0 = (wc * 64 + lr) * 128 + ((lkg ^ (lr & 7)) << 4) + 32768;

    bf16x8 a[4][2], b[4][2];
#pragma unroll
    for (int m = 0; m < 8; m++)
#pragma unroll
        for (int n = 0; n < 4; n++) acc[m][n] = (f32x4){0.f, 0.f, 0.f, 0.f};

#define STG_A(buf, k0, h) do { _Pragma("unroll") for (int jj = 0; jj < 2; jj++) { \
    int j = (h) * 2 + jj; \
    GLOAD16(Aptr + src_off[j] + (k0), L + (buf) * 65536 + j * 8192 + tid * 16); } } while (0)
#define STG_B(buf, k0, h) do { _Pragma("unroll") for (int jj = 0; jj < 2; jj++) { \
    int j = (h) * 2 + jj; \
    GLOAD16(Bptr + src_off[j] + (k0), L + (buf) * 65536 + 32768 + j * 8192 + tid * 16); } } while (0)
#define RD_A(buf, mh) do { _Pragma("unroll") for (int mm = 0; mm < 4; mm++) { \
    int ro = (buf) * 65536 + aoff0 + ((mh) * 4 + mm) * 2048; \
    a[mm][0] = *(const bf16x8*)(L + ro); \
    a[mm][1] = *(const bf16x8*)(L + (ro ^ 64)); } } while (0)
#define RD_B(buf, nh) do { _Pragma("unroll") for (int nn = 0; nn < 2; nn++) { \
    int ro = (buf) * 65536 + boff0 + ((nh) * 2 + nn) * 2048; \
    b[(nh) * 2 + nn][0] = *(const bf16x8*)(L + ro); \
    b[(nh) * 2 + nn][1] = *(const bf16x8*)(L + (ro ^ 64)); } } while (0)
#define MM(mh, nh) do { _Pragma("unroll") for (int mm = 0; mm < 4; mm++) \
    _Pragma("unroll") for (int nn = 0; nn < 2; nn++) \
    _Pragma("unroll") for (int ks = 0; ks < 2; ks++) \
        acc[(mh) * 4 + mm][(nh) * 2 + nn] = \
            mfma16(a[mm][ks], b[(nh) * 2 + nn][ks], acc[(mh) * 4 + mm][(nh) * 2 + nn]); } while (0)
#define BAR   asm volatile("s_barrier" ::: "memory")
#define LGKM0 do { asm volatile("s_waitcnt lgkmcnt(0)" ::: "memory"); \
                   __builtin_amdgcn_sched_barrier(0); } while (0)
#define VMC4  asm volatile("s_waitcnt vmcnt(4)" ::: "memory")
#define PHI   __builtin_amdgcn_s_setprio(1)
#define PLO   __builtin_amdgcn_s_setprio(0)

    STG_A(0, kb, 0); STG_A(0, kb, 1); STG_B(0, kb, 0); STG_B(0, kb, 1);
    STG_B(1, kb + BKG, 0); STG_B(1, kb + BKG, 1);
    VMC4;   // 12 issued, wait <=4 outstanding -> buf0's 8 landed
    BAR;

    const int iters = (kend - kb) / (2 * BKG);
#pragma unroll 1
    for (int t = 0; t < iters; ++t) {
        int k1 = kb + (2 * t + 1) * BKG;
        int k2 = kb + (2 * t + 2) * BKG; if (k2 > kend - BKG) k2 = kend - BKG;
        int k3 = kb + (2 * t + 3) * BKG; if (k3 > kend - BKG) k3 = kend - BKG;
        // P1: compute buf0 (m0-3 x n0-1)
        RD_A(0, 0); RD_B(0, 0); STG_A(1, k1, 0);
        BAR; LGKM0; PHI; MM(0, 0); PLO; BAR;
        // P2: (m0-3 x n2-3)
        RD_B(0, 1); STG_A(1, k1, 1);
        BAR; LGKM0; PHI; MM(0, 1); PLO; BAR;
        // P3: (m4-7 x n0-1); buf0.B reads done -> stage next buf0.B
        RD_A(0, 1); STG_B(0, k2, 0);
        BAR; LGKM0; PHI; MM(1, 0); PLO; BAR;
        // P4: counted wait -> buf1 (P1/P2 A + prev B) landed
        STG_B(0, k2, 1);
        BAR; LGKM0; PHI; MM(1, 1); PLO; VMC4; BAR;
        // P5: compute buf1
        RD_A(1, 0); RD_B(1, 0); STG_A(0, k2, 0);
        BAR; LGKM0; PHI; MM(0, 0); PLO; BAR;
        // P6
        RD_B(1, 1); STG_A(0, k2, 1);
        BAR; LGKM0; PHI; MM(0, 1); PLO; BAR;
        // P7
        RD_A(1, 1); STG_B(1, k3, 0);
        BAR; LGKM0; PHI; MM(1, 0); PLO; BAR;
        // P8: counted wait -> buf0 (P3-P6) landed for next iter's P1
        STG_B(1, k3, 1);
        BAR; LGKM0; PHI; MM(1, 1); PLO; VMC4; BAR;
    }
    asm volatile("s_waitcnt vmcnt(0)" ::: "memory");

#undef STG_A
#undef STG_B
#undef RD_A
#undef RD_B
#undef MM
#undef BAR
#undef LGKM0
#undef VMC4
#undef PHI
#undef PLO
}

// ---------------- fused QKV projection (kv quarters first, then q full-K; XCD-chunked) ----------------
// grid 480. bid<256: kv quarter jobs, XCD x (=bid&7) owns bm in {2x,2x+1} for all
// (nb,ks): i=bid>>3 in [0,32): nb=14+(i>>3), ks=(i>>1)&3, bm=2x+(i&1).
// bid>=256: 224 q FULL-K jobs, same mapping as oproj: e=bid-256, x=e&7, i=e>>3,
// nb=i>>1, bm=2x+(i&1) -> A panels L2-resident per XCD (14x reuse), W streams via LLC.
__global__ __launch_bounds__(512, 2) void qkv_gemm8(
    const unsigned short* __restrict__ xu, const unsigned short* __restrict__ xg,
    const unsigned short* __restrict__ wq0, const unsigned short* __restrict__ wk0,
    const unsigned short* __restrict__ wv0, const unsigned short* __restrict__ wq1,
    const unsigned short* __restrict__ wk1, const unsigned short* __restrict__ wv1,
    const float* __restrict__ bq0, const float* __restrict__ bk0, const float* __restrict__ bv0,
    const float* __restrict__ bq1, const float* __restrict__ bk1, const float* __restrict__ bv1,
    unsigned short* __restrict__ qp, unsigned short* __restrict__ kp,
    unsigned short* __restrict__ vp) {
    __shared__ unsigned short lds[65536];   // 128 KiB
    const int bid = blockIdx.x;
    int nb, ks, bm, kb, klen;
    if (bid < 256) {                    // kv quarter jobs (dispatch first)
        int x = bid & 7, i = bid >> 3;  // 32 jobs per XCD
        nb = 14 + (i >> 3);
        ks = (i >> 1) & 3;
        bm = x * 2 + (i & 1);
        kb = ks * 896; klen = 896;
    } else {                            // q full-K jobs (oproj-style XCD chunking)
        int e = bid - 256;
        int x = e & 7, i = e >> 3;      // 28 jobs per XCD
        nb = i >> 1; bm = x * 2 + (i & 1);
        ks = 0; kb = 0; klen = KDIM;
    }
    const int par = bm >> 3, mb = bm & 7;
    const unsigned short* A = (par ? xg : xu) + (size_t)mb * 256 * KDIM;
    const unsigned short* W;
    const float* bias;
    unsigned short* C;
    int ldc, col0;
    if (nb < 14) {
        W = (par ? wq1 : wq0) + (size_t)nb * 256 * KDIM;
        bias = (par ? bq1 : bq0); C = qp; ldc = NH * HD; col0 = nb * 256;
    } else if (nb < 16) {
        W = (par ? wk1 : wk0) + (size_t)(nb - 14) * 256 * KDIM;
        bias = (par ? bk1 : bk0); C = kp + (size_t)ks * T_TOK * (NKV * HD);
        ldc = NKV * HD; col0 = (nb - 14) * 256;
    } else {
        W = (par ? wv1 : wv0) + (size_t)(nb - 16) * 256 * KDIM;
        bias = (par ? bv1 : bv0); C = vp + (size_t)ks * T_TOK * (NKV * HD);
        ldc = NKV * HD; col0 = (nb - 16) * 256;
    }
    f32x4 acc[8][4];
    gemm256_core(A, W, lds, acc, kb, kb + klen);

    const int lane = threadIdx.x & 63, w = threadIdx.x >> 6;
    const int wr = w >> 2, wc = w & 3, lr = lane & 15, lkg = lane >> 4;
#pragma unroll
    for (int n = 0; n < 4; n++) {
        int colt = col0 + wc * 64 + n * 16 + lr;
        float bb = (ks == 0) ? bias[colt] : 0.f;
#pragma unroll
        for (int m = 0; m < 8; m++) {
#pragma unroll
            for (int rg = 0; rg < 4; rg++) {
                int tr = mb * 256 + wr * 128 + m * 16 + lkg * 4 + rg;
                int tok = 2 * tr + par;
                C[(size_t)tok * ldc + colt] = f2bf(acc[m][n][rg] + bb);
            }
        }
    }
}

// ---------------- output projection (8-phase 256^2, full K, XCD-chunked) ----------------
__global__ __launch_bounds__(512, 2) void oproj_gemm8(
    const unsigned short* __restrict__ au, const unsigned short* __restrict__ ag,
    const unsigned short* __restrict__ wo0, const unsigned short* __restrict__ wo1,
    float* __restrict__ out) {
    __shared__ unsigned short lds[65536];
    const int bid = blockIdx.x;
    const int x = bid & 7, i = bid >> 3;
    const int nb = i >> 1, bm = x * 2 + (i & 1);
    const int par = bm >> 3, mb = bm & 7;
    const unsigned short* A = (par ? ag : au) + (size_t)mb * 256 * KDIM;
    const unsigned short* W = (par ? wo1 : wo0) + (size_t)nb * 256 * KDIM;
    f32x4 acc[8][4];
    gemm256_core(A, W, lds, acc, 0, KDIM);

    const int lane = threadIdx.x & 63, w = threadIdx.x >> 6;
    const int wr = w >> 2, wc = w & 3, lr = lane & 15, lkg = lane >> 4;
#pragma unroll
    for (int n = 0; n < 4; n++) {
        int col = nb * 256 + wc * 64 + n * 16 + lr;
#pragma unroll
        for (int m = 0; m < 8; m++) {
#pragma unroll
            for (int rg = 0; rg < 4; rg++) {
                int tr = mb * 256 + wr * 128 + m * 16 + lkg * 4 + rg;
                int tok = 2 * tr + par;
                out[(size_t)tok * HID + col] = acc[m][n][rg];
            }
        }
    }
}

// ---------------- RMSNorm + RoPE (q: 1 slab, k: 4 partials) + fused vtrans ----------------
__global__ void normrope2(const unsigned short* __restrict__ qp, const unsigned short* __restrict__ kp,
                          const unsigned short* __restrict__ vp,
                          const float* __restrict__ cosb, const float* __restrict__ sinb,
                          const float* __restrict__ qn, const float* __restrict__ kn,
                          const float* __restrict__ qng, const float* __restrict__ kng,
                          unsigned short* __restrict__ q_bf, unsigned short* __restrict__ k_bf,
                          unsigned short* __restrict__ vT) {
    if (blockIdx.y == 8) {   // vtrans path: sum 4 bf16 partials -> vT
        if (blockIdx.x >= 1024) return;
        const int u = blockIdx.x * 2 + (threadIdx.x >> 7);   // 0..2047
        const int d = threadIdx.x & 127;
        const int sh = u >> 7, lb = u & 127;
        const int s = sh >> 2, hv = sh & 3;
        const size_t S = (size_t)T_TOK * NKV * HD;
        unsigned short tmp[8];
#pragma unroll
        for (int i = 0; i < 8; i++) {
            size_t idx = ((size_t)(s * LSEQ + lb * 8 + i)) * (NKV * HD) + hv * HD + d;
            tmp[i] = f2bf(bf2f(vp[idx]) + bf2f(vp[S + idx]) +
                          bf2f(vp[2 * S + idx]) + bf2f(vp[3 * S + idx]));
        }
        *(bf16x8*)(vT + ((size_t)sh * HD + d) * LSEQ + lb * 8) = *(bf16x8*)tmp;
        return;
    }
    const int t = blockIdx.x, w = threadIdx.x >> 6, lane = threadIdx.x & 63;
    const int h = blockIdx.y * 4 + w;
    const bool isq = (h < 28);
    float v0, v1;
    if (isq) {
        const unsigned short* src = qp + (size_t)t * (NH * HD) + h * HD;
        v0 = bf2f(src[lane]);
        v1 = bf2f(src[lane + 64]);
    } else {
        const unsigned short* src = kp + (size_t)t * (NKV * HD) + (h - 28) * HD;
        const size_t S = (size_t)T_TOK * NKV * HD;
        v0 = bf2f(src[lane]) + bf2f(src[S + lane]) + bf2f(src[2 * S + lane]) + bf2f(src[3 * S + lane]);
        v1 = bf2f(src[lane + 64]) + bf2f(src[S + lane + 64]) +
             bf2f(src[2 * S + lane + 64]) + bf2f(src[3 * S + lane + 64]);
    }
    float ss = v0 * v0 + v1 * v1;
#pragma unroll
    for (int off = 32; off >= 1; off >>= 1) ss += __shfl_xor(ss, off, 64);
    float inv = rsqrtf(ss * (1.f / 128.f) + 1e-6f);
    const float* wn = isq ? ((t & 1) ? qng : qn) : ((t & 1) ? kng : kn);
    float n0 = v0 * inv * wn[lane], n1 = v1 * inv * wn[lane + 64];
    float c0 = cosb[(size_t)t * HD + lane], c1 = cosb[(size_t)t * HD + lane + 64];
    float s0 = sinb[(size_t)t * HD + lane], s1 = sinb[(size_t)t * HD + lane + 64];
    float o0 = n0 * c0 - n1 * s0;
    float o1 = n1 * c1 + n0 * s1;
    unsigned short* dst = isq ? q_bf + (size_t)t * (NH * HD) + h * HD
                              : k_bf + (size_t)t * (NKV * HD) + (h - 28) * HD;
    dst[lane] = f2bf(o0);
    dst[lane + 64] = f2bf(o1);
}

// ---------------- flash attention (swapped QK^T, QBLK=128, dbuf LDS) + fused wo cvt ----------------
__global__ __launch_bounds__(512, 4) void attn_fwd(
    const unsigned short* __restrict__ q_bf, const unsigned short* __restrict__ k_bf,
    const unsigned short* __restrict__ vT,
    unsigned short* __restrict__ au, unsigned short* __restrict__ ag,
    const float* __restrict__ wof, const float* __restrict__ wogf,
    unsigned short* __restrict__ wob, unsigned short* __restrict__ wogb) {
    __shared__ unsigned short kt[2][64 * 128];   // K tiles, swizzled
    __shared__ unsigned short vt[2][128 * 64];   // V^T tiles, swizzled
    __shared__ unsigned short pt[8][16 * 64];    // per-wave P [q=16 rows of 128B]

    const int bid = blockIdx.x;
    const int tid = threadIdx.x;
    if (bid < NCVT) {   // conversion path (no LDS use)
        const size_t n4 = (size_t)KDIM * KDIM / 4;
        for (size_t i = (size_t)bid * 512 + tid; i < 2 * n4; i += (size_t)NCVT * 512) {
            const float* sp = (i < n4) ? wof : wogf;
            unsigned short* dp = (i < n4) ? wob : wogb;
            size_t j = (i < n4) ? i : i - n4;
            float4 v = reinterpret_cast<const float4*>(sp)[j];
            ushort4 o;
            o.x = f2bf(v.x); o.y = f2bf(v.y); o.z = f2bf(v.z); o.w = f2bf(v.w);
            reinterpret_cast<ushort4*>(dp)[j] = o;
        }
        return;
    }
    const int e = bid - NCVT;
    const int qbk = 7 - (e / 112);            // heavy (long-K) blocks dispatch first
    const int rem = e % 112;
    const int h = rem >> 2, s = rem & 3;
    const int hk = h / 7;
    const int lane = tid & 63, w = tid >> 6;
    const int lr = lane & 15, lkg = lane >> 4;
    const int qg = qbk * 128 + w * 16 + lr;   // this lane's q row (global in segment)

    bf16x8 qf[4];
    {
        const unsigned short* qp =
            q_bf + ((size_t)(s * LSEQ + qg)) * (NH * HD) + h * HD;
#pragma unroll
        for (int kk = 0; kk < 4; kk++) qf[kk] = *(const bf16x8*)(qp + kk * 32 + lkg * 8);
    }
    asm volatile("s_waitcnt vmcnt(0)" ::: "memory");

    float m_r = -1e30f, l_r = 0.f;
    f32x4 accO[8];
#pragma unroll
    for (int dn = 0; dn < 8; dn++) accO[dn] = (f32x4){0.f, 0.f, 0.f, 0.f};

    const float scale = 0.08838834764831843f;
    const int nkt = 2 * qbk + 2;              // kv tiles of 64 (causal)

#define STAGE_KV(buf, ktile) do { _Pragma("unroll") for (int i = 0; i < 2; i++) { \
    int o = i * 8192 + tid * 16; \
    { int r = o >> 8; int sc = ((o >> 4) & 15) ^ (r & 7); \
      GLOAD16(k_bf + ((size_t)(s * LSEQ + (ktile) * 64 + r)) * (NKV * HD) + hk * HD + sc * 8, \
              (char*)kt[buf] + o); } \
    { int r = o >> 7; int sc = ((o >> 4) & 7) ^ (r & 7); \
      GLOAD16(vT + ((size_t)((s * NKV + hk) * HD + r)) * LSEQ + (ktile) * 64 + sc * 8, \
              (char*)vt[buf] + o); } } } while (0)

    STAGE_KV(0, 0);

#pragma unroll 1
    for (int ktile = 0; ktile < nkt; ++ktile) {
        const int cur = ktile & 1;
        if (ktile + 1 < nkt) {
            STAGE_KV(cur ^ 1, ktile + 1);                     // overlap next-tile loads
            asm volatile("s_waitcnt vmcnt(4)" ::: "memory");  // this tile's 4 landed
        } else {
            asm volatile("s_waitcnt vmcnt(0)" ::: "memory");
        }
        asm volatile("s_barrier" ::: "memory");

        // S^T = mfma(K, Q): accT[n][rg] = S[q=lr][kv = ktile*64 + n*16 + lkg*4 + rg]
        f32x4 accT[4];
#pragma unroll
        for (int n = 0; n < 4; n++) accT[n] = (f32x4){0.f, 0.f, 0.f, 0.f};
        __builtin_amdgcn_s_setprio(1);
#pragma unroll
        for (int n = 0; n < 4; n++) {
            int r = n * 16 + lr;
#pragma unroll
            for (int kk = 0; kk < 4; kk++) {
                bf16x8 kf = *(const bf16x8*)((const char*)kt[cur] + r * 256 +
                                             (((kk * 4 + lkg) ^ (r & 7)) << 4));
                accT[n] = mfma16(kf, qf[kk], accT[n]);   // swapped operands
            }
        }
        __builtin_amdgcn_s_setprio(0);
        // scale + causal mask + in-lane row max
        float mnew = -1e30f;
#pragma unroll
        for (int n = 0; n < 4; n++) {
#pragma unroll
            for (int rg = 0; rg < 4; rg++) {
                int kvg = ktile * 64 + n * 16 + lkg * 4 + rg;
                float sv = accT[n][rg] * scale;
                sv = (kvg <= qg) ? sv : -1e30f;
                accT[n][rg] = sv;
                mnew = fmaxf(mnew, sv);
            }
        }
        mnew = fmaxf(mnew, __shfl_xor(mnew, 16, 64));
        mnew = fmaxf(mnew, __shfl_xor(mnew, 32, 64));
        // defer-max (T13)
        if (__any(mnew > m_r + 8.f)) {
            float mc = fmaxf(m_r, mnew);
            float alpha = __expf(m_r - mc);
            m_r = mc;
            l_r *= alpha;
            float ab[4];
#pragma unroll
            for (int rg = 0; rg < 4; rg++) ab[rg] = __shfl(alpha, lkg * 4 + rg, 64);
#pragma unroll
            for (int dn = 0; dn < 8; dn++)
#pragma unroll
                for (int rg = 0; rg < 4; rg++) accO[dn][rg] *= ab[rg];
        }
        // P = exp(S - m): in-lane sum + packed 8B stores to P[q=lr][kv]
        float ls = 0.f;
#pragma unroll
        for (int n = 0; n < 4; n++) {
            unsigned short p4[4];
#pragma unroll
            for (int rg = 0; rg < 4; rg++) {
                float p = __expf(accT[n][rg] - m_r);
                ls += p;
                p4[rg] = f2bf(p);
            }
            int byte = lr * 128 + ((((n * 2 + (lkg >> 1)) ^ (lr & 7))) << 4) + (lkg & 1) * 8;
            *(uint2*)((char*)pt[w] + byte) = *(uint2*)p4;
        }
        ls += __shfl_xor(ls, 16, 64);
        ls += __shfl_xor(ls, 32, 64);
        l_r += ls;
        // O += P V  (pf read layout identical to P write layout above)
        __builtin_amdgcn_s_setprio(1);
#pragma unroll
        for (int kk2 = 0; kk2 < 2; kk2++) {
            bf16x8 pf = *(const bf16x8*)((const char*)pt[w] + lr * 128 +
                                         (((kk2 * 4 + lkg) ^ (lr & 7)) << 4));
#pragma unroll
            for (int dn = 0; dn < 8; dn++) {
                int r2 = dn * 16 + lr;
                bf16x8 vf = *(const bf16x8*)((const char*)vt[cur] + r2 * 128 +
                                             (((kk2 * 4 + lkg) ^ (r2 & 7)) << 4));
                accO[dn] = mfma16(pf, vf, accO[dn]);
            }
        }
        __builtin_amdgcn_s_setprio(0);
        asm volatile("s_barrier" ::: "memory");   // reads of buf[cur] done -> free for t+2
    }
#undef STAGE_KV

    // epilogue: broadcast l to accO layout (q = lkg*4+rg), divide, store
    float lb4[4];
#pragma unroll
    for (int rg = 0; rg < 4; rg++) lb4[rg] = __shfl(l_r, lkg * 4 + rg, 64);
#pragma unroll
    for (int dn = 0; dn < 8; dn++) {
#pragma unroll
        for (int rg = 0; rg < 4; rg++) {
            int row = qbk * 128 + w * 16 + lkg * 4 + rg;
            int t = s * LSEQ + row;
            unsigned short* dst = ((t & 1) ? ag : au) + (size_t)(t >> 1) * (NH * HD) +
                                  h * HD + dn * 16 + lr;
            *dst = f2bf(accO[dn][rg] / lb4[rg]);
        }
    }
}

// ---------------- host ----------------
extern "C" void kernel_launch(void* const* d_in, const int* in_sizes, int n_in,
                              void* d_out, int out_size, void* d_ws, size_t ws_size,
                              hipStream_t stream) {
    const float* x    = (const float*)d_in[0];
    const float* cosb = (const float*)d_in[1];
    const float* sinb = (const float*)d_in[2];
    const float* wq   = (const float*)d_in[3];
    const float* bq   = (const float*)d_in[4];
    const float* wk   = (const float*)d_in[5];
    const float* bk   = (const float*)d_in[6];
    const float* wv   = (const float*)d_in[7];
    const float* bv   = (const float*)d_in[8];
    const float* wo   = (const float*)d_in[9];
    const float* wqg  = (const float*)d_in[10];
    const float* bqg  = (const float*)d_in[11];
    const float* wkg  = (const float*)d_in[12];
    const float* bkg  = (const float*)d_in[13];
    const float* wvg  = (const float*)d_in[14];
    const float* bvg  = (const float*)d_in[15];
    const float* wog  = (const float*)d_in[16];
    const float* qn   = (const float*)d_in[17];
    const float* kn   = (const float*)d_in[18];
    const float* qng  = (const float*)d_in[19];
    const float* kng  = (const float*)d_in[20];
    float* out = (float*)d_out;

    char* ws = (char*)d_ws;
    size_t off = 0;
    auto alloc = [&](size_t bytes) -> char* {
        char* p = ws + off;
        off += (bytes + 255) & ~(size_t)255;
        return p;
    };
    const size_t WQ_E = (size_t)3584 * 3584;
    const size_t WK_E = (size_t)512 * 3584;
    unsigned short* wqb  = (unsigned short*)alloc(WQ_E * 2);   // dead after qkv -> reused
    unsigned short* wqgb = (unsigned short*)alloc(WQ_E * 2);   // dead after qkv -> reused
    unsigned short* wob  = (unsigned short*)alloc(WQ_E * 2);
    unsigned short* wogb = (unsigned short*)alloc(WQ_E * 2);
    unsigned short* wkb  = (unsigned short*)alloc(WK_E * 2);
    unsigned short* wkgb = (unsigned short*)alloc(WK_E * 2);
    unsigned short* wvb  = (unsigned short*)alloc(WK_E * 2);
    unsigned short* wvgb = (unsigned short*)alloc(WK_E * 2);
    unsigned short* xu   = (unsigned short*)alloc((size_t)2048 * HID * 2);
    unsigned short* xg   = (unsigned short*)alloc((size_t)2048 * HID * 2);
    unsigned short* qp = (unsigned short*)alloc((size_t)T_TOK * (NH * HD) * 2);       // 1 slab
    unsigned short* kp = (unsigned short*)alloc((size_t)4 * T_TOK * (NKV * HD) * 2);  // 4 slabs
    unsigned short* vp = (unsigned short*)alloc((size_t)4 * T_TOK * (NKV * HD) * 2);  // 4 slabs
    // q_bf/k_bf/vT alias the dead wqb/wqgb region (51.4 MB >= 29.4+4.2+4.2)
    unsigned short* q_bf = wqb;
    unsigned short* k_bf = wqb + (size_t)T_TOK * (NH * HD);
    unsigned short* vTb  = k_bf + (size_t)T_TOK * (NKV * HD);
    unsigned short* au = qp;                        // aliases dead qp region (29.4 MB)
    unsigned short* ag = au + (size_t)2048 * (NH * HD);

    if (ws_size < off) return;

    cvt_front<<<dim3((XN4 + 2 * WQ4 + 4 * WK4) / 256), 256, 0, stream>>>(
        x, wq, wqg, wk, wkg, wv, wvg,
        xu, xg, wqb, wqgb, wkb, wkgb, wvb, wvgb);

    qkv_gemm8<<<dim3(480), 512, 0, stream>>>(xu, xg, wqb, wkb, wvb, wqgb, wkgb, wvgb,
                                             bq, bk, bv, bqg, bkg, bvg, qp, kp, vp);
    normrope2<<<dim3(T_TOK, 9), 256, 0, stream>>>(qp, kp, vp, cosb, sinb,
                                                  qn, kn, qng, kng, q_bf, k_bf, vTb);
    attn_fwd<<<dim3(NCVT + 896), 512, 0, stream>>>(q_bf, k_bf, vTb, au, ag,
                                                   wo, wog, wob, wogb);
    oproj_gemm8<<<dim3(224), 512, 0, stream>>>(au, ag, wob, wogb, out);
}

// Round 19
// 389.737 us; speedup vs baseline: 1.4059x; 1.0050x over previous
//
#include <hip/hip_runtime.h>
#include <hip/hip_bf16.h>

// Problem constants
#define T_TOK 4096
#define HID   3584
#define NH    28
#define NKV   4
#define HD    128
#define SEG   4
#define LSEQ  1024
#define KDIM  3584   // K of all GEMMs (HID == NH*HD)
#define BKG   64     // GEMM K-tile
#define NCVT  128    // cvt blocks fused into attn

typedef __attribute__((ext_vector_type(8))) short bf16x8;
typedef __attribute__((ext_vector_type(4))) float f32x4;

#define GLOAD16(g, l) __builtin_amdgcn_global_load_lds( \
    (const __attribute__((address_space(1))) void*)(g), \
    (__attribute__((address_space(3))) void*)(l), 16, 0, 0)

__device__ __forceinline__ unsigned short f2bf(float f) {
    unsigned u = __float_as_uint(f);
    return (unsigned short)((u + 0x7fffu + ((u >> 16) & 1u)) >> 16);
}
__device__ __forceinline__ float bf2f(unsigned short u) {
    return __uint_as_float(((unsigned)u) << 16);
}

__device__ __forceinline__ f32x4 mfma16(bf16x8 a, bf16x8 b, f32x4 c) {
    return __builtin_amdgcn_mfma_f32_16x16x32_bf16(a, b, c, 0, 0, 0);
}

// ---------------- fused front conversion (x parity-split + 6 weight matrices) ----------------
#define XN4  3670016
#define WQ4  3211264
#define WK4  458752
__global__ void cvt_front(const float* __restrict__ x,
                          const float* __restrict__ wq, const float* __restrict__ wqg,
                          const float* __restrict__ wk, const float* __restrict__ wkg,
                          const float* __restrict__ wv, const float* __restrict__ wvg,
                          unsigned short* __restrict__ xu, unsigned short* __restrict__ xg,
                          unsigned short* __restrict__ wqb, unsigned short* __restrict__ wqgb,
                          unsigned short* __restrict__ wkb, unsigned short* __restrict__ wkgb,
                          unsigned short* __restrict__ wvb, unsigned short* __restrict__ wvgb) {
    size_t i = (size_t)blockIdx.x * 256 + threadIdx.x;
    if (i < XN4) {   // x: parity-compacted split
        int t = (int)(i / (HID / 4));
        int c = (int)(i - (size_t)t * (HID / 4));
        float4 v = reinterpret_cast<const float4*>(x)[i];
        ushort4 o;
        o.x = f2bf(v.x); o.y = f2bf(v.y); o.z = f2bf(v.z); o.w = f2bf(v.w);
        unsigned short* dst = ((t & 1) ? xg : xu) + (size_t)(t >> 1) * HID + c * 4;
        *reinterpret_cast<ushort4*>(dst) = o;
        return;
    }
    i -= XN4;
    const float* s; unsigned short* d;
    if (i < 2 * (size_t)WQ4) {
        if (i < WQ4) { s = wq; d = wqb; } else { i -= WQ4; s = wqg; d = wqgb; }
    } else {
        i -= 2 * (size_t)WQ4;
        size_t seg = i / WK4; i -= seg * WK4;
        switch (seg) {
            case 0: s = wk;  d = wkb;  break;
            case 1: s = wkg; d = wkgb; break;
            case 2: s = wv;  d = wvb;  break;
            default: s = wvg; d = wvgb; break;
        }
    }
    float4 v = reinterpret_cast<const float4*>(s)[i];
    ushort4 o;
    o.x = f2bf(v.x); o.y = f2bf(v.y); o.z = f2bf(v.z); o.w = f2bf(v.w);
    reinterpret_cast<ushort4*>(d)[i] = o;
}

// ---------------- 256x256 8-phase GEMM core (R1/R7-proven), with K-range ----------------
__device__ __forceinline__ void gemm256_core(const unsigned short* __restrict__ Aptr,
                                             const unsigned short* __restrict__ Bptr,
                                             unsigned short* ldsbase, f32x4 (&acc)[8][4],
                                             int kb, int kend) {
    const int tid = threadIdx.x;               // 0..511
    const int lane = tid & 63, w = tid >> 6;
    const int wr = w >> 2, wc = w & 3;         // wave grid 2M x 4N
    const int lr = lane & 15, lkg = lane >> 4;
    char* const L = (char*)ldsbase;

    int src_off[4];
#pragma unroll
    for (int j = 0; j < 4; j++) {
        int r = j * 64 + (tid >> 3);
        int clog = (tid & 7) ^ ((tid >> 3) & 7);
        src_off[j] = r * KDIM + clog * 8;
    }
    const int aoff0 = (wr * 128 + lr) * 128 + ((lkg ^ (lr & 7)) << 4);
    const int boff0 = (wc * 64 + lr) * 128 + ((lkg ^ (lr & 7)) << 4) + 32768;

    bf16x8 a[4][2], b[4][2];
#pragma unroll
    for (int m = 0; m < 8; m++)
#pragma unroll
        for (int n = 0; n < 4; n++) acc[m][n] = (f32x4){0.f, 0.f, 0.f, 0.f};

#define STG_A(buf, k0, h) do { _Pragma("unroll") for (int jj = 0; jj < 2; jj++) { \
    int j = (h) * 2 + jj; \
    GLOAD16(Aptr + src_off[j] + (k0), L + (buf) * 65536 + j * 8192 + tid * 16); } } while (0)
#define STG_B(buf, k0, h) do { _Pragma("unroll") for (int jj = 0; jj < 2; jj++) { \
    int j = (h) * 2 + jj; \
    GLOAD16(Bptr + src_off[j] + (k0), L + (buf) * 65536 + 32768 + j * 8192 + tid * 16); } } while (0)
#define RD_A(buf, mh) do { _Pragma("unroll") for (int mm = 0; mm < 4; mm++) { \
    int ro = (buf) * 65536 + aoff0 + ((mh) * 4 + mm) * 2048; \
    a[mm][0] = *(const bf16x8*)(L + ro); \
    a[mm][1] = *(const bf16x8*)(L + (ro ^ 64)); } } while (0)
#define RD_B(buf, nh) do { _Pragma("unroll") for (int nn = 0; nn < 2; nn++) { \
    int ro = (buf) * 65536 + boff0 + ((nh) * 2 + nn) * 2048; \
    b[(nh) * 2 + nn][0] = *(const bf16x8*)(L + ro); \
    b[(nh) * 2 + nn][1] = *(const bf16x8*)(L + (ro ^ 64)); } } while (0)
#define MM(mh, nh) do { _Pragma("unroll") for (int mm = 0; mm < 4; mm++) \
    _Pragma("unroll") for (int nn = 0; nn < 2; nn++) \
    _Pragma("unroll") for (int ks = 0; ks < 2; ks++) \
        acc[(mh) * 4 + mm][(nh) * 2 + nn] = \
            mfma16(a[mm][ks], b[(nh) * 2 + nn][ks], acc[(mh) * 4 + mm][(nh) * 2 + nn]); } while (0)
#define BAR   asm volatile("s_barrier" ::: "memory")
#define LGKM0 do { asm volatile("s_waitcnt lgkmcnt(0)" ::: "memory"); \
                   __builtin_amdgcn_sched_barrier(0); } while (0)
#define VMC4  asm volatile("s_waitcnt vmcnt(4)" ::: "memory")
#define PHI   __builtin_amdgcn_s_setprio(1)
#define PLO   __builtin_amdgcn_s_setprio(0)

    STG_A(0, kb, 0); STG_A(0, kb, 1); STG_B(0, kb, 0); STG_B(0, kb, 1);
    STG_B(1, kb + BKG, 0); STG_B(1, kb + BKG, 1);
    VMC4;   // 12 issued, wait <=4 outstanding -> buf0's 8 landed
    BAR;

    const int iters = (kend - kb) / (2 * BKG);
#pragma unroll 1
    for (int t = 0; t < iters; ++t) {
        int k1 = kb + (2 * t + 1) * BKG;
        int k2 = kb + (2 * t + 2) * BKG; if (k2 > kend - BKG) k2 = kend - BKG;
        int k3 = kb + (2 * t + 3) * BKG; if (k3 > kend - BKG) k3 = kend - BKG;
        // P1: compute buf0 (m0-3 x n0-1)
        RD_A(0, 0); RD_B(0, 0); STG_A(1, k1, 0);
        BAR; LGKM0; PHI; MM(0, 0); PLO; BAR;
        // P2: (m0-3 x n2-3)
        RD_B(0, 1); STG_A(1, k1, 1);
        BAR; LGKM0; PHI; MM(0, 1); PLO; BAR;
        // P3: (m4-7 x n0-1); buf0.B reads done -> stage next buf0.B
        RD_A(0, 1); STG_B(0, k2, 0);
        BAR; LGKM0; PHI; MM(1, 0); PLO; BAR;
        // P4: counted wait -> buf1 (P1/P2 A + prev B) landed
        STG_B(0, k2, 1);
        BAR; LGKM0; PHI; MM(1, 1); PLO; VMC4; BAR;
        // P5: compute buf1
        RD_A(1, 0); RD_B(1, 0); STG_A(0, k2, 0);
        BAR; LGKM0; PHI; MM(0, 0); PLO; BAR;
        // P6
        RD_B(1, 1); STG_A(0, k2, 1);
        BAR; LGKM0; PHI; MM(0, 1); PLO; BAR;
        // P7
        RD_A(1, 1); STG_B(1, k3, 0);
        BAR; LGKM0; PHI; MM(1, 0); PLO; BAR;
        // P8: counted wait -> buf0 (P3-P6) landed for next iter's P1
        STG_B(1, k3, 1);
        BAR; LGKM0; PHI; MM(1, 1); PLO; VMC4; BAR;
    }
    asm volatile("s_waitcnt vmcnt(0)" ::: "memory");

#undef STG_A
#undef STG_B
#undef RD_A
#undef RD_B
#undef MM
#undef BAR
#undef LGKM0
#undef VMC4
#undef PHI
#undef PLO
}

// ---------------- fused QKV projection (kv quarters first, then q full-K; XCD-chunked) ----------------
__global__ __launch_bounds__(512, 2) void qkv_gemm8(
    const unsigned short* __restrict__ xu, const unsigned short* __restrict__ xg,
    const unsigned short* __restrict__ wq0, const unsigned short* __restrict__ wk0,
    const unsigned short* __restrict__ wv0, const unsigned short* __restrict__ wq1,
    const unsigned short* __restrict__ wk1, const unsigned short* __restrict__ wv1,
    const float* __restrict__ bq0, const float* __restrict__ bk0, const float* __restrict__ bv0,
    const float* __restrict__ bq1, const float* __restrict__ bk1, const float* __restrict__ bv1,
    unsigned short* __restrict__ qp, unsigned short* __restrict__ kp,
    unsigned short* __restrict__ vp) {
    __shared__ unsigned short lds[65536];   // 128 KiB
    const int bid = blockIdx.x;
    int nb, ks, bm, kb, klen;
    if (bid < 256) {                    // kv quarter jobs (dispatch first)
        int x = bid & 7, i = bid >> 3;  // 32 jobs per XCD
        nb = 14 + (i >> 3);
        ks = (i >> 1) & 3;
        bm = x * 2 + (i & 1);
        kb = ks * 896; klen = 896;
    } else {                            // q full-K jobs (oproj-style XCD chunking)
        int e = bid - 256;
        int x = e & 7, i = e >> 3;      // 28 jobs per XCD
        nb = i >> 1; bm = x * 2 + (i & 1);
        ks = 0; kb = 0; klen = KDIM;
    }
    const int par = bm >> 3, mb = bm & 7;
    const unsigned short* A = (par ? xg : xu) + (size_t)mb * 256 * KDIM;
    const unsigned short* W;
    const float* bias;
    unsigned short* C;
    int ldc, col0;
    if (nb < 14) {
        W = (par ? wq1 : wq0) + (size_t)nb * 256 * KDIM;
        bias = (par ? bq1 : bq0); C = qp; ldc = NH * HD; col0 = nb * 256;
    } else if (nb < 16) {
        W = (par ? wk1 : wk0) + (size_t)(nb - 14) * 256 * KDIM;
        bias = (par ? bk1 : bk0); C = kp + (size_t)ks * T_TOK * (NKV * HD);
        ldc = NKV * HD; col0 = (nb - 14) * 256;
    } else {
        W = (par ? wv1 : wv0) + (size_t)(nb - 16) * 256 * KDIM;
        bias = (par ? bv1 : bv0); C = vp + (size_t)ks * T_TOK * (NKV * HD);
        ldc = NKV * HD; col0 = (nb - 16) * 256;
    }
    f32x4 acc[8][4];
    gemm256_core(A, W, lds, acc, kb, kb + klen);

    const int lane = threadIdx.x & 63, w = threadIdx.x >> 6;
    const int wr = w >> 2, wc = w & 3, lr = lane & 15, lkg = lane >> 4;
#pragma unroll
    for (int n = 0; n < 4; n++) {
        int colt = col0 + wc * 64 + n * 16 + lr;
        float bb = (ks == 0) ? bias[colt] : 0.f;
#pragma unroll
        for (int m = 0; m < 8; m++) {
#pragma unroll
            for (int rg = 0; rg < 4; rg++) {
                int tr = mb * 256 + wr * 128 + m * 16 + lkg * 4 + rg;
                int tok = 2 * tr + par;
                C[(size_t)tok * ldc + colt] = f2bf(acc[m][n][rg] + bb);
            }
        }
    }
}

// ---------------- output projection (8-phase 256^2, full K, XCD-chunked) ----------------
__global__ __launch_bounds__(512, 2) void oproj_gemm8(
    const unsigned short* __restrict__ au, const unsigned short* __restrict__ ag,
    const unsigned short* __restrict__ wo0, const unsigned short* __restrict__ wo1,
    float* __restrict__ out) {
    __shared__ unsigned short lds[65536];
    const int bid = blockIdx.x;
    const int x = bid & 7, i = bid >> 3;
    const int nb = i >> 1, bm = x * 2 + (i & 1);
    const int par = bm >> 3, mb = bm & 7;
    const unsigned short* A = (par ? ag : au) + (size_t)mb * 256 * KDIM;
    const unsigned short* W = (par ? wo1 : wo0) + (size_t)nb * 256 * KDIM;
    f32x4 acc[8][4];
    gemm256_core(A, W, lds, acc, 0, KDIM);

    const int lane = threadIdx.x & 63, w = threadIdx.x >> 6;
    const int wr = w >> 2, wc = w & 3, lr = lane & 15, lkg = lane >> 4;
#pragma unroll
    for (int n = 0; n < 4; n++) {
        int col = nb * 256 + wc * 64 + n * 16 + lr;
#pragma unroll
        for (int m = 0; m < 8; m++) {
#pragma unroll
            for (int rg = 0; rg < 4; rg++) {
                int tr = mb * 256 + wr * 128 + m * 16 + lkg * 4 + rg;
                int tok = 2 * tr + par;
                out[(size_t)tok * HID + col] = acc[m][n][rg];
            }
        }
    }
}

// ---------------- RMSNorm + RoPE (q: 1 slab, k: 4 partials) + fused vtrans ----------------
__global__ void normrope2(const unsigned short* __restrict__ qp, const unsigned short* __restrict__ kp,
                          const unsigned short* __restrict__ vp,
                          const float* __restrict__ cosb, const float* __restrict__ sinb,
                          const float* __restrict__ qn, const float* __restrict__ kn,
                          const float* __restrict__ qng, const float* __restrict__ kng,
                          unsigned short* __restrict__ q_bf, unsigned short* __restrict__ k_bf,
                          unsigned short* __restrict__ vT) {
    if (blockIdx.y == 8) {   // vtrans path: sum 4 bf16 partials -> vT
        if (blockIdx.x >= 1024) return;
        const int u = blockIdx.x * 2 + (threadIdx.x >> 7);   // 0..2047
        const int d = threadIdx.x & 127;
        const int sh = u >> 7, lb = u & 127;
        const int s = sh >> 2, hv = sh & 3;
        const size_t S = (size_t)T_TOK * NKV * HD;
        unsigned short tmp[8];
#pragma unroll
        for (int i = 0; i < 8; i++) {
            size_t idx = ((size_t)(s * LSEQ + lb * 8 + i)) * (NKV * HD) + hv * HD + d;
            tmp[i] = f2bf(bf2f(vp[idx]) + bf2f(vp[S + idx]) +
                          bf2f(vp[2 * S + idx]) + bf2f(vp[3 * S + idx]));
        }
        *(bf16x8*)(vT + ((size_t)sh * HD + d) * LSEQ + lb * 8) = *(bf16x8*)tmp;
        return;
    }
    const int t = blockIdx.x, w = threadIdx.x >> 6, lane = threadIdx.x & 63;
    const int h = blockIdx.y * 4 + w;
    const bool isq = (h < 28);
    float v0, v1;
    if (isq) {
        const unsigned short* src = qp + (size_t)t * (NH * HD) + h * HD;
        v0 = bf2f(src[lane]);
        v1 = bf2f(src[lane + 64]);
    } else {
        const unsigned short* src = kp + (size_t)t * (NKV * HD) + (h - 28) * HD;
        const size_t S = (size_t)T_TOK * NKV * HD;
        v0 = bf2f(src[lane]) + bf2f(src[S + lane]) + bf2f(src[2 * S + lane]) + bf2f(src[3 * S + lane]);
        v1 = bf2f(src[lane + 64]) + bf2f(src[S + lane + 64]) +
             bf2f(src[2 * S + lane + 64]) + bf2f(src[3 * S + lane + 64]);
    }
    float ss = v0 * v0 + v1 * v1;
#pragma unroll
    for (int off = 32; off >= 1; off >>= 1) ss += __shfl_xor(ss, off, 64);
    float inv = rsqrtf(ss * (1.f / 128.f) + 1e-6f);
    const float* wn = isq ? ((t & 1) ? qng : qn) : ((t & 1) ? kng : kn);
    float n0 = v0 * inv * wn[lane], n1 = v1 * inv * wn[lane + 64];
    float c0 = cosb[(size_t)t * HD + lane], c1 = cosb[(size_t)t * HD + lane + 64];
    float s0 = sinb[(size_t)t * HD + lane], s1 = sinb[(size_t)t * HD + lane + 64];
    float o0 = n0 * c0 - n1 * s0;
    float o1 = n1 * c1 + n0 * s1;
    unsigned short* dst = isq ? q_bf + (size_t)t * (NH * HD) + h * HD
                              : k_bf + (size_t)t * (NKV * HD) + (h - 28) * HD;
    dst[lane] = f2bf(o0);
    dst[lane + 64] = f2bf(o1);
}

// ---------------- flash attention (swapped QK^T, QBLK=128, dbuf LDS) + fused wo cvt ----------------
// Within each heavy-first qbk stripe of 112 blocks, decode rem -> x=rem&7, i=rem>>3,
// pair = x*14+i: each XCD's 14 blocks span ~4 consecutive h (<=2 hk) -> KV L2-resident.
__global__ __launch_bounds__(512, 4) void attn_fwd(
    const unsigned short* __restrict__ q_bf, const unsigned short* __restrict__ k_bf,
    const unsigned short* __restrict__ vT,
    unsigned short* __restrict__ au, unsigned short* __restrict__ ag,
    const float* __restrict__ wof, const float* __restrict__ wogf,
    unsigned short* __restrict__ wob, unsigned short* __restrict__ wogb) {
    __shared__ unsigned short kt[2][64 * 128];   // K tiles, swizzled
    __shared__ unsigned short vt[2][128 * 64];   // V^T tiles, swizzled
    __shared__ unsigned short pt[8][16 * 64];    // per-wave P [q=16 rows of 128B]

    const int bid = blockIdx.x;
    const int tid = threadIdx.x;
    if (bid < NCVT) {   // conversion path (no LDS use)
        const size_t n4 = (size_t)KDIM * KDIM / 4;
        for (size_t i = (size_t)bid * 512 + tid; i < 2 * n4; i += (size_t)NCVT * 512) {
            const float* sp = (i < n4) ? wof : wogf;
            unsigned short* dp = (i < n4) ? wob : wogb;
            size_t j = (i < n4) ? i : i - n4;
            float4 v = reinterpret_cast<const float4*>(sp)[j];
            ushort4 o;
            o.x = f2bf(v.x); o.y = f2bf(v.y); o.z = f2bf(v.z); o.w = f2bf(v.w);
            reinterpret_cast<ushort4*>(dp)[j] = o;
        }
        return;
    }
    const int e = bid - NCVT;
    const int qbk = 7 - (e / 112);            // heavy (long-K) blocks dispatch first
    const int rem = e % 112;
    const int pair = (rem & 7) * 14 + (rem >> 3);   // XCD-chunked (h,s) assignment
    const int h = pair >> 2, s = pair & 3;
    const int hk = h / 7;
    const int lane = tid & 63, w = tid >> 6;
    const int lr = lane & 15, lkg = lane >> 4;
    const int qg = qbk * 128 + w * 16 + lr;   // this lane's q row (global in segment)

    bf16x8 qf[4];
    {
        const unsigned short* qp =
            q_bf + ((size_t)(s * LSEQ + qg)) * (NH * HD) + h * HD;
#pragma unroll
        for (int kk = 0; kk < 4; kk++) qf[kk] = *(const bf16x8*)(qp + kk * 32 + lkg * 8);
    }
    asm volatile("s_waitcnt vmcnt(0)" ::: "memory");

    float m_r = -1e30f, l_r = 0.f;
    f32x4 accO[8];
#pragma unroll
    for (int dn = 0; dn < 8; dn++) accO[dn] = (f32x4){0.f, 0.f, 0.f, 0.f};

    const float scale = 0.08838834764831843f;
    const int nkt = 2 * qbk + 2;              // kv tiles of 64 (causal)

#define STAGE_KV(buf, ktile) do { _Pragma("unroll") for (int i = 0; i < 2; i++) { \
    int o = i * 8192 + tid * 16; \
    { int r = o >> 8; int sc = ((o >> 4) & 15) ^ (r & 7); \
      GLOAD16(k_bf + ((size_t)(s * LSEQ + (ktile) * 64 + r)) * (NKV * HD) + hk * HD + sc * 8, \
              (char*)kt[buf] + o); } \
    { int r = o >> 7; int sc = ((o >> 4) & 7) ^ (r & 7); \
      GLOAD16(vT + ((size_t)((s * NKV + hk) * HD + r)) * LSEQ + (ktile) * 64 + sc * 8, \
              (char*)vt[buf] + o); } } } while (0)

    STAGE_KV(0, 0);

#pragma unroll 1
    for (int ktile = 0; ktile < nkt; ++ktile) {
        const int cur = ktile & 1;
        if (ktile + 1 < nkt) {
            STAGE_KV(cur ^ 1, ktile + 1);                     // overlap next-tile loads
            asm volatile("s_waitcnt vmcnt(4)" ::: "memory");  // this tile's 4 landed
        } else {
            asm volatile("s_waitcnt vmcnt(0)" ::: "memory");
        }
        asm volatile("s_barrier" ::: "memory");

        // S^T = mfma(K, Q): accT[n][rg] = S[q=lr][kv = ktile*64 + n*16 + lkg*4 + rg]
        f32x4 accT[4];
#pragma unroll
        for (int n = 0; n < 4; n++) accT[n] = (f32x4){0.f, 0.f, 0.f, 0.f};
        __builtin_amdgcn_s_setprio(1);
#pragma unroll
        for (int n = 0; n < 4; n++) {
            int r = n * 16 + lr;
#pragma unroll
            for (int kk = 0; kk < 4; kk++) {
                bf16x8 kf = *(const bf16x8*)((const char*)kt[cur] + r * 256 +
                                             (((kk * 4 + lkg) ^ (r & 7)) << 4));
                accT[n] = mfma16(kf, qf[kk], accT[n]);   // swapped operands
            }
        }
        __builtin_amdgcn_s_setprio(0);
        // scale + causal mask + in-lane row max
        float mnew = -1e30f;
#pragma unroll
        for (int n = 0; n < 4; n++) {
#pragma unroll
            for (int rg = 0; rg < 4; rg++) {
                int kvg = ktile * 64 + n * 16 + lkg * 4 + rg;
                float sv = accT[n][rg] * scale;
                sv = (kvg <= qg) ? sv : -1e30f;
                accT[n][rg] = sv;
                mnew = fmaxf(mnew, sv);
            }
        }
        mnew = fmaxf(mnew, __shfl_xor(mnew, 16, 64));
        mnew = fmaxf(mnew, __shfl_xor(mnew, 32, 64));
        // defer-max (T13)
        if (__any(mnew > m_r + 8.f)) {
            float mc = fmaxf(m_r, mnew);
            float alpha = __expf(m_r - mc);
            m_r = mc;
            l_r *= alpha;
            float ab[4];
#pragma unroll
            for (int rg = 0; rg < 4; rg++) ab[rg] = __shfl(alpha, lkg * 4 + rg, 64);
#pragma unroll
            for (int dn = 0; dn < 8; dn++)
#pragma unroll
                for (int rg = 0; rg < 4; rg++) accO[dn][rg] *= ab[rg];
        }
        // P = exp(S - m): in-lane sum + packed 8B stores to P[q=lr][kv]
        float ls = 0.f;
#pragma unroll
        for (int n = 0; n < 4; n++) {
            unsigned short p4[4];
#pragma unroll
            for (int rg = 0; rg < 4; rg++) {
                float p = __expf(accT[n][rg] - m_r);
                ls += p;
                p4[rg] = f2bf(p);
            }
            int byte = lr * 128 + ((((n * 2 + (lkg >> 1)) ^ (lr & 7))) << 4) + (lkg & 1) * 8;
            *(uint2*)((char*)pt[w] + byte) = *(uint2*)p4;
        }
        ls += __shfl_xor(ls, 16, 64);
        ls += __shfl_xor(ls, 32, 64);
        l_r += ls;
        // O += P V  (pf read layout identical to P write layout above)
        __builtin_amdgcn_s_setprio(1);
#pragma unroll
        for (int kk2 = 0; kk2 < 2; kk2++) {
            bf16x8 pf = *(const bf16x8*)((const char*)pt[w] + lr * 128 +
                                         (((kk2 * 4 + lkg) ^ (lr & 7)) << 4));
#pragma unroll
            for (int dn = 0; dn < 8; dn++) {
                int r2 = dn * 16 + lr;
                bf16x8 vf = *(const bf16x8*)((const char*)vt[cur] + r2 * 128 +
                                             (((kk2 * 4 + lkg) ^ (r2 & 7)) << 4));
                accO[dn] = mfma16(pf, vf, accO[dn]);
            }
        }
        __builtin_amdgcn_s_setprio(0);
        asm volatile("s_barrier" ::: "memory");   // reads of buf[cur] done -> free for t+2
    }
#undef STAGE_KV

    // epilogue: broadcast l to accO layout (q = lkg*4+rg), divide, store
    float lb4[4];
#pragma unroll
    for (int rg = 0; rg < 4; rg++) lb4[rg] = __shfl(l_r, lkg * 4 + rg, 64);
#pragma unroll
    for (int dn = 0; dn < 8; dn++) {
#pragma unroll
        for (int rg = 0; rg < 4; rg++) {
            int row = qbk * 128 + w * 16 + lkg * 4 + rg;
            int t = s * LSEQ + row;
            unsigned short* dst = ((t & 1) ? ag : au) + (size_t)(t >> 1) * (NH * HD) +
                                  h * HD + dn * 16 + lr;
            *dst = f2bf(accO[dn][rg] / lb4[rg]);
        }
    }
}

// ---------------- host ----------------
extern "C" void kernel_launch(void* const* d_in, const int* in_sizes, int n_in,
                              void* d_out, int out_size, void* d_ws, size_t ws_size,
                              hipStream_t stream) {
    const float* x    = (const float*)d_in[0];
    const float* cosb = (const float*)d_in[1];
    const float* sinb = (const float*)d_in[2];
    const float* wq   = (const float*)d_in[3];
    const float* bq   = (const float*)d_in[4];
    const float* wk   = (const float*)d_in[5];
    const float* bk   = (const float*)d_in[6];
    const float* wv   = (const float*)d_in[7];
    const float* bv   = (const float*)d_in[8];
    const float* wo   = (const float*)d_in[9];
    const float* wqg  = (const float*)d_in[10];
    const float* bqg  = (const float*)d_in[11];
    const float* wkg  = (const float*)d_in[12];
    const float* bkg  = (const float*)d_in[13];
    const float* wvg  = (const float*)d_in[14];
    const float* bvg  = (const float*)d_in[15];
    const float* wog  = (const float*)d_in[16];
    const float* qn   = (const float*)d_in[17];
    const float* kn   = (const float*)d_in[18];
    const float* qng  = (const float*)d_in[19];
    const float* kng  = (const float*)d_in[20];
    float* out = (float*)d_out;

    char* ws = (char*)d_ws;
    size_t off = 0;
    auto alloc = [&](size_t bytes) -> char* {
        char* p = ws + off;
        off += (bytes + 255) & ~(size_t)255;
        return p;
    };
    const size_t WQ_E = (size_t)3584 * 3584;
    const size_t WK_E = (size_t)512 * 3584;
    unsigned short* wqb  = (unsigned short*)alloc(WQ_E * 2);   // dead after qkv -> reused
    unsigned short* wqgb = (unsigned short*)alloc(WQ_E * 2);   // dead after qkv -> reused
    unsigned short* wob  = (unsigned short*)alloc(WQ_E * 2);
    unsigned short* wogb = (unsigned short*)alloc(WQ_E * 2);
    unsigned short* wkb  = (unsigned short*)alloc(WK_E * 2);
    unsigned short* wkgb = (unsigned short*)alloc(WK_E * 2);
    unsigned short* wvb  = (unsigned short*)alloc(WK_E * 2);
    unsigned short* wvgb = (unsigned short*)alloc(WK_E * 2);
    unsigned short* xu   = (unsigned short*)alloc((size_t)2048 * HID * 2);
    unsigned short* xg   = (unsigned short*)alloc((size_t)2048 * HID * 2);
    unsigned short* qp = (unsigned short*)alloc((size_t)T_TOK * (NH * HD) * 2);       // 1 slab
    unsigned short* kp = (unsigned short*)alloc((size_t)4 * T_TOK * (NKV * HD) * 2);  // 4 slabs
    unsigned short* vp = (unsigned short*)alloc((size_t)4 * T_TOK * (NKV * HD) * 2);  // 4 slabs
    // q_bf/k_bf/vT alias the dead wqb/wqgb region (51.4 MB >= 29.4+4.2+4.2)
    unsigned short* q_bf = wqb;
    unsigned short* k_bf = wqb + (size_t)T_TOK * (NH * HD);
    unsigned short* vTb  = k_bf + (size_t)T_TOK * (NKV * HD);
    unsigned short* au = qp;                        // aliases dead qp region (29.4 MB)
    unsigned short* ag = au + (size_t)2048 * (NH * HD);

    if (ws_size < off) return;

    cvt_front<<<dim3((XN4 + 2 * WQ4 + 4 * WK4) / 256), 256, 0, stream>>>(
        x, wq, wqg, wk, wkg, wv, wvg,
        xu, xg, wqb, wqgb, wkb, wkgb, wvb, wvgb);

    qkv_gemm8<<<dim3(480), 512, 0, stream>>>(xu, xg, wqb, wkb, wvb, wqgb, wkgb, wvgb,
                                             bq, bk, bv, bqg, bkg, bvg, qp, kp, vp);
    normrope2<<<dim3(T_TOK, 9), 256, 0, stream>>>(qp, kp, vp, cosb, sinb,
                                                  qn, kn, qng, kng, q_bf, k_bf, vTb);
    attn_fwd<<<dim3(NCVT + 896), 512, 0, stream>>>(q_bf, k_bf, vTb, au, ag,
                                                   wo, wog, wob, wogb);
    oproj_gemm8<<<dim3(224), 512, 0, stream>>>(au, ag, wob, wogb, out);
}